// Round 8
// baseline (3090.166 us; speedup 1.0000x reference)
//
#include <hip/hip_runtime.h>
#include <cstdint>
#include <cstddef>

typedef __attribute__((ext_vector_type(8))) __bf16 bf16x8;
typedef __attribute__((ext_vector_type(4))) float f32x4;

static constexpr int kNS   = 8192;
static constexpr int kNW   = 65536;
static constexpr int kNSEC = 1024;
static constexpr int kEW   = 131072;
static constexpr int kES   = 262144;
static constexpr int kESEC = 16384;

__device__ __forceinline__ float eluf(float x)  { return x > 0.f ? x : (__expf(x) - 1.f); }
__device__ __forceinline__ float sigmf(float x) { return 1.f / (1.f + __expf(-x)); }

// async global -> LDS, 16 bytes per lane (dest must be linear in lane order)
__device__ __forceinline__ void gload16(const __bf16* g, __bf16* l) {
  __builtin_amdgcn_global_load_lds((const __attribute__((address_space(1))) unsigned int*)g,
                                   (__attribute__((address_space(3))) unsigned int*)l,
                                   16, 0, 0);
}

// ---------------------------------------------------------------------------
// Weight convert + transpose: W[K][N] f32 -> Wt[N][KP] bf16 (zero-pad k>=K)
// ---------------------------------------------------------------------------
__global__ __launch_bounds__(256) void conv_transpose(const float* __restrict__ W, int K, int N,
                                                      __bf16* __restrict__ Wt, int KP) {
  __shared__ float t[64][33];
  const int nb = blockIdx.x * 32, kb = blockIdx.y * 64;
  const int tx = threadIdx.x & 31, ty = threadIdx.x >> 5;
#pragma unroll
  for (int i = ty; i < 64; i += 8) {
    const int k = kb + i;
    t[i][tx] = (k < K) ? W[(long)k * N + nb + tx] : 0.f;
  }
  __syncthreads();
  union BU { __bf16 b; unsigned short u; };
#pragma unroll
  for (int i = ty; i < 32; i += 8) {
    BU b0, b1;
    b0.b = (__bf16)t[tx * 2][i];
    b1.b = (__bf16)t[tx * 2 + 1][i];
    const unsigned int pk = ((unsigned int)b1.u << 16) | b0.u;
    *(unsigned int*)(Wt + (long)(nb + i) * KP + kb + tx * 2) = pk;
  }
}

__global__ __launch_bounds__(256) void conv_bf(const float* __restrict__ in, __bf16* __restrict__ outb, long n) {
  long i = (long)blockIdx.x * blockDim.x + threadIdx.x;
  if (i < n) outb[i] = (__bf16)in[i];
}

// ---------------------------------------------------------------------------
// Head vectors, 6 jobs in one launch: out[h][k] = sum_c W[k][h*640+c]*a[h][c]
// ---------------------------------------------------------------------------
struct HVJ { const float* W; const float* a; float* o; int Kd; int KP; };
struct HVJobs { HVJ j[6]; };

__global__ __launch_bounds__(256) void head_vecs6(HVJobs jb) {
  const HVJ J = jb.j[blockIdx.z];
  const int h = blockIdx.x;
  const int lane = threadIdx.x & 63;
  const int k = blockIdx.y * 4 + (threadIdx.x >> 6);
  if (k >= J.KP) return;
  float s = 0.f;
  if (k < J.Kd) {
    const float* wr = J.W + (long)k * 5120 + h * 640;
    const float* ar = J.a + h * 640;
    for (int c = lane; c < 640; c += 64) s += wr[c] * ar[c];
  }
  for (int o2 = 32; o2; o2 >>= 1) s += __shfl_down(s, o2);
  if (lane == 0) J.o[h * J.KP + k] = (k < J.Kd) ? s : 0.f;
}

// Combined FFN bias: bc[n] = sum_k l1_b[k]*l2_w[k][n] + l2_b[n]
__global__ __launch_bounds__(256) void comb_bias(const float* __restrict__ l1_b, const float* __restrict__ l2_w,
                                                 const float* __restrict__ l2_b, float* __restrict__ bc) {
  const int n = blockIdx.x * 256 + threadIdx.x;
  if (n >= 640) return;
  float s = l2_b[n];
  for (int k = 0; k < 2048; ++k) s += l1_b[k] * l2_w[(long)k * 640 + n];
  bc[n] = s;
}

// ---------------------------------------------------------------------------
// Attention logits: out[n][h] = X[n,:Kd] . vec[h,:Kd]    (1 wave per node)
// ---------------------------------------------------------------------------
__global__ __launch_bounds__(256) void att_logits(const float* __restrict__ X, int ldx, int Kd,
                                                  const float* __restrict__ vec, int KP,
                                                  float* __restrict__ outl, int N) {
  const int lane = threadIdx.x & 63;
  const int node = blockIdx.x * 4 + (threadIdx.x >> 6);
  if (node >= N) return;
  const float* xr = X + (long)node * ldx;
  float p[8];
#pragma unroll
  for (int h = 0; h < 8; ++h) p[h] = 0.f;
  for (int k = lane; k < Kd; k += 64) {
    const float xv = xr[k];
#pragma unroll
    for (int h = 0; h < 8; ++h) p[h] += xv * vec[h * KP + k];
  }
#pragma unroll
  for (int h = 0; h < 8; ++h) {
    float v = p[h];
    for (int o2 = 32; o2; o2 >>= 1) v += __shfl_down(v, o2);
    if (lane == 0) outl[(long)node * 8 + h] = v;
  }
}

// Fused 4-way logits over the same X (reads X once): Kd == KP == 640
__global__ __launch_bounds__(256) void att_logits4(const float* __restrict__ X,
                                                   const float* __restrict__ v0, const float* __restrict__ v1,
                                                   const float* __restrict__ v2, const float* __restrict__ v3,
                                                   float* __restrict__ o0, float* __restrict__ o1,
                                                   float* __restrict__ o2, float* __restrict__ o3, int N) {
  const int lane = threadIdx.x & 63;
  const int node = blockIdx.x * 4 + (threadIdx.x >> 6);
  if (node >= N) return;
  const float* xr = X + (long)node * 640;
  float p[4][8];
#pragma unroll
  for (int s = 0; s < 4; ++s)
#pragma unroll
    for (int h = 0; h < 8; ++h) p[s][h] = 0.f;
  for (int k = lane; k < 640; k += 64) {
    const float xv = xr[k];
#pragma unroll
    for (int h = 0; h < 8; ++h) {
      p[0][h] += xv * v0[h * 640 + k];
      p[1][h] += xv * v1[h * 640 + k];
      p[2][h] += xv * v2[h * 640 + k];
      p[3][h] += xv * v3[h * 640 + k];
    }
  }
  float* outs[4] = {o0, o1, o2, o3};
#pragma unroll
  for (int s = 0; s < 4; ++s)
#pragma unroll
    for (int h = 0; h < 8; ++h) {
      float v = p[s][h];
      for (int o2v = 32; o2v; o2v >>= 1) v += __shfl_down(v, o2v);
      if (lane == 0) outs[s][(long)node * 8 + h] = v;
    }
}

// ---------------------------------------------------------------------------
// CSR build (3 edge lists per launch)
// ---------------------------------------------------------------------------
__global__ __launch_bounds__(256) void edge_count3(const int* __restrict__ d0, int E0, int* __restrict__ c0,
                                                   const int* __restrict__ d1, int E1, int* __restrict__ c1,
                                                   const int* __restrict__ d2, int E2, int* __restrict__ c2) {
  const int gid = blockIdx.x * blockDim.x + threadIdx.x;
  if (gid < E0) atomicAdd(&c0[d0[gid]], 1);
  else if (gid < E0 + E1) atomicAdd(&c1[d1[gid - E0]], 1);
  else if (gid < E0 + E1 + E2) atomicAdd(&c2[d2[gid - E0 - E1]], 1);
}

__global__ __launch_bounds__(1024) void scan_off3(const int* __restrict__ c0, int* __restrict__ o0,
                                                  const int* __restrict__ c1, int* __restrict__ o1,
                                                  const int* __restrict__ c2, int* __restrict__ o2) {
  const int* cnt = blockIdx.x == 0 ? c0 : (blockIdx.x == 1 ? c1 : c2);
  int* offo = blockIdx.x == 0 ? o0 : (blockIdx.x == 1 ? o1 : o2);
  __shared__ int part[1024];
  const int tid = threadIdx.x;
  const int base = tid * 8;
  int loc[8];
  int s = 0;
#pragma unroll
  for (int i = 0; i < 8; ++i) { loc[i] = s; s += cnt[base + i]; }
  part[tid] = s;
  __syncthreads();
  for (int d2 = 1; d2 < 1024; d2 <<= 1) {
    int v = (tid >= d2) ? part[tid - d2] : 0;
    __syncthreads();
    part[tid] += v;
    __syncthreads();
  }
  const int pre = (tid > 0) ? part[tid - 1] : 0;
#pragma unroll
  for (int i = 0; i < 8; ++i) offo[base + i] = pre + loc[i];
  if (tid == 1023) offo[8192] = part[1023];
}

__global__ __launch_bounds__(256) void edge_fill3(
    const int* __restrict__ s0, const int* __restrict__ d0, int E0, const int* __restrict__ of0, int* __restrict__ cu0, int* __restrict__ sr0,
    const int* __restrict__ s1, const int* __restrict__ d1, int E1, const int* __restrict__ of1, int* __restrict__ cu1, int* __restrict__ sr1,
    const int* __restrict__ s2, const int* __restrict__ d2, int E2, const int* __restrict__ of2, int* __restrict__ cu2, int* __restrict__ sr2) {
  const int gid = blockIdx.x * blockDim.x + threadIdx.x;
  if (gid < E0) {
    const int d = d0[gid];
    sr0[of0[d] + atomicAdd(&cu0[d], 1)] = s0[gid];
  } else if (gid < E0 + E1) {
    const int g = gid - E0, d = d1[g];
    sr1[of1[d] + atomicAdd(&cu1[d], 1)] = s1[g];
  } else if (gid < E0 + E1 + E2) {
    const int g = gid - E0 - E1, d = d2[g];
    sr2[of2[d] + atomicAdd(&cu2[d], 1)] = s2[g];
  }
}

// ---------------------------------------------------------------------------
// GAT aggregation, f32 X (float4) -- used for the word layer (F=300)
// ---------------------------------------------------------------------------
template <int FPAD, int F, bool XPH, bool BIASELU>
__global__ __launch_bounds__(256) void gat_agg(const int* __restrict__ seg_off, const int* __restrict__ ssrc,
                                               const float* __restrict__ als, const float* __restrict__ ald,
                                               const float* __restrict__ X, int ldx,
                                               __bf16* __restrict__ outp, int ldo,
                                               const float* __restrict__ bias) {
  constexpr int C4 = F / 4;
  constexpr int ITEMS = 8 * C4;
  constexpr int L = (ITEMS + 255) / 256;
  const int d = blockIdx.x;
  const int tid = threadIdx.x;
  const int o0 = seg_off[d], o1 = seg_off[d + 1];
  const int deg = o1 - o0;
  __shared__ float exl[64][8];
  __shared__ int ssl[64];
  __shared__ float aldd[8];
  __shared__ float den_s[8];
  if (tid < 8) { aldd[tid] = ald[(long)d * 8 + tid]; den_s[tid] = 0.f; }
  f32x4 acc[L];
  int hh[L], xo[L], oo[L];
  bool vld[L];
#pragma unroll
  for (int l = 0; l < L; ++l) {
    const int idx = tid + l * 256;
    vld[l] = (idx < ITEMS);
    const int h = vld[l] ? (idx / C4) : 0;
    const int c = vld[l] ? (idx - h * C4) : 0;
    hh[l] = h;
    xo[l] = (XPH ? h * F : 0) + c * 4;
    oo[l] = h * FPAD + c * 4;
#pragma unroll
    for (int r = 0; r < 4; ++r) acc[l][r] = 0.f;
  }
  __syncthreads();
  for (int base = 0; base < deg; base += 64) {
    const int nc = min(64, deg - base);
    if (tid < nc) ssl[tid] = ssrc[o0 + base + tid];
    __syncthreads();
    for (int t = tid; t < nc * 8; t += 256) {
      const int e = t >> 3, h = t & 7;
      float v = als[(long)ssl[e] * 8 + h] + aldd[h];
      v = v > 0.f ? v : 0.2f * v;
      exl[e][h] = __expf(v);
    }
    __syncthreads();
    if (tid < 8) {
      float s = 0.f;
      for (int e = 0; e < nc; ++e) s += exl[e][tid];
      den_s[tid] += s;
    }
    for (int e = 0; e < nc; ++e) {
      const float* xr = X + (long)ssl[e] * ldx;
      const float* ex8 = exl[e];
#pragma unroll
      for (int l = 0; l < L; ++l)
        if (vld[l]) {
          const f32x4 v = *(const f32x4*)(xr + xo[l]);
          acc[l] += ex8[hh[l]] * v;
        }
    }
    __syncthreads();
  }
#pragma unroll
  for (int l = 0; l < L; ++l) {
    if (!vld[l]) continue;
    const float dinv = 1.f / (den_s[hh[l]] + 1e-16f);
#pragma unroll
    for (int j = 0; j < 4; ++j) {
      float r = acc[l][j] * dinv;
      if constexpr (BIASELU) { r += bias[oo[l] + j]; r = eluf(r); }
      outp[(long)d * ldo + oo[l] + j] = (__bf16)r;
    }
  }
}

// ---------------------------------------------------------------------------
// GAT aggregation, bf16 X (bf16x8, 16B/load) -- sentence & section layers
// ---------------------------------------------------------------------------
template <int FPAD, int F, bool XPH, bool BIASELU>
__global__ __launch_bounds__(256) void gat_agg_bf(const int* __restrict__ seg_off, const int* __restrict__ ssrc,
                                                  const float* __restrict__ als, const float* __restrict__ ald,
                                                  const __bf16* __restrict__ X, int ldx,
                                                  __bf16* __restrict__ outp, int ldo,
                                                  const float* __restrict__ bias) {
  constexpr int C8 = F / 8;
  constexpr int ITEMS = 8 * C8;
  constexpr int L = (ITEMS + 255) / 256;
  const int d = blockIdx.x;
  const int tid = threadIdx.x;
  const int o0 = seg_off[d], o1 = seg_off[d + 1];
  const int deg = o1 - o0;
  __shared__ float exl[64][8];
  __shared__ int ssl[64];
  __shared__ float aldd[8];
  __shared__ float den_s[8];
  if (tid < 8) { aldd[tid] = ald[(long)d * 8 + tid]; den_s[tid] = 0.f; }
  float acc[L][8];
  int hh[L], xo[L], oo[L];
  bool vld[L];
#pragma unroll
  for (int l = 0; l < L; ++l) {
    const int idx = tid + l * 256;
    vld[l] = (idx < ITEMS);
    const int h = vld[l] ? (idx / C8) : 0;
    const int c = vld[l] ? (idx - h * C8) : 0;
    hh[l] = h;
    xo[l] = (XPH ? h * F : 0) + c * 8;
    oo[l] = h * FPAD + c * 8;
#pragma unroll
    for (int r = 0; r < 8; ++r) acc[l][r] = 0.f;
  }
  __syncthreads();
  for (int base = 0; base < deg; base += 64) {
    const int nc = min(64, deg - base);
    if (tid < nc) ssl[tid] = ssrc[o0 + base + tid];
    __syncthreads();
    for (int t = tid; t < nc * 8; t += 256) {
      const int e = t >> 3, h = t & 7;
      float v = als[(long)ssl[e] * 8 + h] + aldd[h];
      v = v > 0.f ? v : 0.2f * v;
      exl[e][h] = __expf(v);
    }
    __syncthreads();
    if (tid < 8) {
      float s = 0.f;
      for (int e = 0; e < nc; ++e) s += exl[e][tid];
      den_s[tid] += s;
    }
    for (int e = 0; e < nc; ++e) {
      const __bf16* xr = X + (long)ssl[e] * ldx;
      const float* ex8 = exl[e];
#pragma unroll
      for (int l = 0; l < L; ++l)
        if (vld[l]) {
          const bf16x8 v = *(const bf16x8*)(xr + xo[l]);
          const float w = ex8[hh[l]];
#pragma unroll
          for (int r = 0; r < 8; ++r) acc[l][r] += w * (float)v[r];
        }
    }
    __syncthreads();
  }
#pragma unroll
  for (int l = 0; l < L; ++l) {
    if (!vld[l]) continue;
    const float dinv = 1.f / (den_s[hh[l]] + 1e-16f);
#pragma unroll
    for (int j = 0; j < 8; ++j) {
      float r = acc[l][j] * dinv;
      if constexpr (BIASELU) { r += bias[oo[l] + j]; r = eluf(r); }
      outp[(long)d * ldo + oo[l] + j] = (__bf16)r;
    }
  }
}

// ---------------------------------------------------------------------------
// 128x128-tile MFMA GEMM (m97-class, 2-barrier) -- small/batched GEMMs.
// EPI: 0 store f32 | 1 bias+ELU->bf16 | 2 sigmoid-gate mix->bf16
//      3 bias->bf16 | 4 bias+residual->f32 | 5 store bf16
// ---------------------------------------------------------------------------
template <int EPI>
__global__ __launch_bounds__(256) void gemm_bt(
    const __bf16* __restrict__ A, int lda, const __bf16* __restrict__ A2, int ksplit,
    const __bf16* __restrict__ Bt, int ldb, int K,
    void* __restrict__ Cout, int ldc,
    const float* __restrict__ bias,
    const __bf16* __restrict__ Xg, const __bf16* __restrict__ Yg, int ldxy,
    const float* __restrict__ Res, int ldres,
    long a_zs, long bt_zs, long c_zs, int b_zs) {
  __shared__ __bf16 sA[2][128 * 32];
  __shared__ __bf16 sB[2][128 * 32];
  const int tid = threadIdx.x;
  const int z = blockIdx.z;
  const int m0 = blockIdx.y * 128, n0 = blockIdx.x * 128;
  const __bf16* Ab = A + (long)z * a_zs;
  const __bf16* A2b = A2 ? A2 + (long)z * a_zs : nullptr;
  const __bf16* Btb = Bt + (long)z * bt_zs;
  const int lane = tid & 63;
  const int wv = tid >> 6, wr = wv >> 1, wc = wv & 1;
  const int fr = lane & 15, fq = lane >> 4;

  const int r0 = tid >> 2, r1 = r0 + 64;
  const int csw = (((tid & 3) ^ ((r0 >> 1) & 3)) * 8);
  const int ldst0 = tid * 8;
  const int ldst1 = 2048 + tid * 8;

  f32x4 acc[4][4];
#pragma unroll
  for (int i = 0; i < 4; ++i)
#pragma unroll
    for (int j = 0; j < 4; ++j)
#pragma unroll
      for (int r = 0; r < 4; ++r) acc[i][j][r] = 0.f;

  const int fsw = (fq ^ ((fr >> 1) & 3)) * 8;
  int aof[4], bof[4];
#pragma unroll
  for (int i = 0; i < 4; ++i) {
    aof[i] = (wr * 64 + i * 16 + fr) * 32 + fsw;
    bof[i] = (wc * 64 + i * 16 + fr) * 32 + fsw;
  }

  const int nkt = K >> 5;
  auto stage = [&](int buf, int kt) {
    const int k0 = kt * 32;
    const __bf16* As = Ab;
    int kr = k0;
    if (A2b && k0 >= ksplit) { As = A2b; kr = k0 - ksplit; }
    gload16(As + (long)(m0 + r0) * lda + kr + csw, &sA[buf][ldst0]);
    gload16(As + (long)(m0 + r1) * lda + kr + csw, &sA[buf][ldst1]);
    gload16(Btb + (long)(n0 + r0) * ldb + k0 + csw, &sB[buf][ldst0]);
    gload16(Btb + (long)(n0 + r1) * ldb + k0 + csw, &sB[buf][ldst1]);
  };

  stage(0, 0);
  for (int kt = 0; kt < nkt; ++kt) {
    const int cur = kt & 1;
    __syncthreads();
    if (kt + 1 < nkt) stage(cur ^ 1, kt + 1);
    bf16x8 af[4], bfv[4];
#pragma unroll
    for (int i = 0; i < 4; ++i) {
      af[i] = *(const bf16x8*)(&sA[cur][aof[i]]);
      bfv[i] = *(const bf16x8*)(&sB[cur][bof[i]]);
    }
#pragma unroll
    for (int i = 0; i < 4; ++i)
#pragma unroll
      for (int j = 0; j < 4; ++j)
        acc[i][j] = __builtin_amdgcn_mfma_f32_16x16x32_bf16(af[i], bfv[j], acc[i][j], 0, 0, 0);
  }

  const float* biasb = bias ? bias + (long)z * b_zs : nullptr;
#pragma unroll
  for (int i = 0; i < 4; ++i) {
#pragma unroll
    for (int j = 0; j < 4; ++j) {
#pragma unroll
      for (int r = 0; r < 4; ++r) {
        const int mm = m0 + wr * 64 + i * 16 + fq * 4 + r;
        const int nn = n0 + wc * 64 + j * 16 + fr;
        const float v = acc[i][j][r];
        const long cidx = (long)mm * ldc + nn + (long)z * c_zs;
        if constexpr (EPI == 0) {
          ((float*)Cout)[cidx] = v;
        } else if constexpr (EPI == 1) {
          ((__bf16*)Cout)[cidx] = (__bf16)eluf(v + biasb[nn]);
        } else if constexpr (EPI == 2) {
          const float zt = sigmf(v + biasb[nn]);
          const float x = (float)Xg[(long)mm * ldxy + nn];
          const float y = (float)Yg[(long)mm * ldxy + nn];
          ((__bf16*)Cout)[cidx] = (__bf16)(zt * x + (1.f - zt) * y);
        } else if constexpr (EPI == 3) {
          ((__bf16*)Cout)[cidx] = (__bf16)(v + biasb[nn]);
        } else if constexpr (EPI == 4) {
          ((float*)Cout)[cidx] = v + biasb[nn] + Res[(long)mm * ldres + nn];
        } else {
          ((__bf16*)Cout)[cidx] = (__bf16)v;
        }
      }
    }
  }
}

// ---------------------------------------------------------------------------
// 256x256-tile 8-wave MFMA GEMM, hoisted-reads pipeline (R7 structure).
// NEW: blocks with blockIdx.x >= ngemm run a grid-stride weight-transpose
// (tW[tK][tN] f32 -> tWt[tN][tKP] bf16) using sA as scratch -- fills the
// partial last scheduling round (640 tiles on 256 CUs = 2.5 rounds) with
// the NEXT GEMM's weight transpose, removing that serial launch.
// EPI: 2 sigmoid-gate mix->bf16 | 3 bias->bf16
// ---------------------------------------------------------------------------
template <int EPI>
__global__ __launch_bounds__(512, 2) void gemm256(
    const __bf16* __restrict__ A, int lda, const __bf16* __restrict__ A2, int ksplit,
    const __bf16* __restrict__ Bt, int ldb, int K,
    void* __restrict__ Cout, int ldc,
    const float* __restrict__ bias,
    const __bf16* __restrict__ Xg, const __bf16* __restrict__ Yg, int ldxy,
    int nn_tiles, int ngemm,
    const float* __restrict__ tW, __bf16* __restrict__ tWt, int tK, int tN, int tKP) {
  __shared__ __bf16 sA[2][2][256 * 32];
  __shared__ __bf16 sB[2][2][256 * 32];
  const int tid = threadIdx.x;
  const int lin = blockIdx.x;

  if (lin >= ngemm) {
    // ---- transpose worker (512 threads) ----
    if (tW) {
      float* sc = (float*)&sA[0][0][0];  // 64*33 f32 scratch
      const int nworkers = gridDim.x - ngemm;
      const int wid = lin - ngemm;
      const int ntx = tN >> 5, nty = tKP >> 6;
      const int tx = tid & 31, ty = tid >> 5;  // ty 0..15
      union BU { __bf16 b; unsigned short u; };
      for (int tile = wid; tile < ntx * nty; tile += nworkers) {
        const int nb = (tile % ntx) * 32, kb = (tile / ntx) * 64;
#pragma unroll
        for (int i = ty; i < 64; i += 16) {
          const int k = kb + i;
          sc[i * 33 + tx] = (k < tK) ? tW[(long)k * tN + nb + tx] : 0.f;
        }
        __syncthreads();
#pragma unroll
        for (int i = ty; i < 32; i += 16) {
          BU b0, b1;
          b0.b = (__bf16)sc[(tx * 2) * 33 + i];
          b1.b = (__bf16)sc[(tx * 2 + 1) * 33 + i];
          const unsigned int pk = ((unsigned int)b1.u << 16) | b0.u;
          *(unsigned int*)(tWt + (long)(nb + i) * tKP + kb + tx * 2) = pk;
        }
        __syncthreads();
      }
    }
    return;
  }

  // bijective XCD swizzle over the GEMM blocks only
  const int nwg = ngemm;
  const int qq = nwg >> 3, rr = nwg & 7;
  const int xcd = lin & 7, pos = lin >> 3;
  const int swz = (xcd < rr ? xcd * (qq + 1) : rr * (qq + 1) + (xcd - rr) * qq) + pos;
  const int m0 = (swz / nn_tiles) * 256;
  const int n0 = (swz % nn_tiles) * 256;

  const int lane = tid & 63;
  const int wv = tid >> 6, wm = wv >> 2, wn = wv & 3;
  const int fr = lane & 15, fq = lane >> 4;

  const int srow = tid >> 2;
  const int pslot = tid & 3;

  auto stageA = [&](int bp, int tt, int kk) {
    const int kcol0 = tt * 64 + kk * 32;
    const __bf16* src = A;
    int kc = kcol0;
    if (A2 && kcol0 >= ksplit) { src = A2; kc = kcol0 - ksplit; }
    __bf16* dst = &sA[bp][kk][0];
#pragma unroll
    for (int i = 0; i < 2; ++i) {
      const int r = i * 128 + srow;
      const int l = pslot ^ ((r >> 1) & 3);
      gload16(src + (long)(m0 + r) * lda + kc + l * 8, dst + (i * 512 + tid) * 8);
    }
  };
  auto stageB = [&](int bp, int tt, int kk) {
    const int kcol0 = tt * 64 + kk * 32;
    __bf16* dst = &sB[bp][kk][0];
#pragma unroll
    for (int i = 0; i < 2; ++i) {
      const int r = i * 128 + srow;
      const int l = pslot ^ ((r >> 1) & 3);
      gload16(Bt + (long)(n0 + r) * ldb + kcol0 + l * 8, dst + (i * 512 + tid) * 8);
    }
  };

  int aoff[8], boff[4];
#pragma unroll
  for (int mf = 0; mf < 8; ++mf) {
    const int ra = wm * 128 + mf * 16 + fr;
    aoff[mf] = ra * 32 + ((fq ^ ((ra >> 1) & 3)) * 8);
  }
#pragma unroll
  for (int nf = 0; nf < 4; ++nf) {
    const int rb = wn * 64 + nf * 16 + fr;
    boff[nf] = rb * 32 + ((fq ^ ((rb >> 1) & 3)) * 8);
  }

  f32x4 acc[8][4];
#pragma unroll
  for (int i = 0; i < 8; ++i)
#pragma unroll
    for (int j = 0; j < 4; ++j)
#pragma unroll
      for (int r = 0; r < 4; ++r) acc[i][j][r] = 0.f;

  const int nkt = K >> 6;

  bf16x8 aA[4], aB[4], bA[4], bB[4];

  stageA(0, 0, 0); stageB(0, 0, 0); stageA(0, 0, 1); stageB(0, 0, 1);
  asm volatile("s_waitcnt vmcnt(4)" ::: "memory");
  __builtin_amdgcn_s_barrier();
#pragma unroll
  for (int mf = 0; mf < 4; ++mf) aA[mf] = *(const bf16x8*)(&sA[0][0][aoff[mf]]);
#pragma unroll
  for (int nf = 0; nf < 4; ++nf) bA[nf] = *(const bf16x8*)(&sB[0][0][boff[nf]]);

  for (int t = 0; t < nkt; ++t) {
    const int cb = t & 1, nb = cb ^ 1;
    const bool pf = (t + 1 < nkt);

    // q1 reads (cb k0, A 4-7) -- hoisted above q0 MFMA
#pragma unroll
    for (int mf = 0; mf < 4; ++mf) aB[mf] = *(const bf16x8*)(&sA[cb][0][aoff[4 + mf]]);
    if (pf) stageA(nb, t + 1, 0);
    asm volatile("s_waitcnt lgkmcnt(4)" ::: "memory");
    __builtin_amdgcn_sched_barrier(0);
    __builtin_amdgcn_s_setprio(1);
#pragma unroll
    for (int mf = 0; mf < 4; ++mf)
#pragma unroll
      for (int nf = 0; nf < 4; ++nf)
        acc[mf][nf] = __builtin_amdgcn_mfma_f32_16x16x32_bf16(aA[mf], bA[nf], acc[mf][nf], 0, 0, 0);
    __builtin_amdgcn_s_setprio(0);
    __builtin_amdgcn_sched_barrier(0);

    if (pf) stageB(nb, t + 1, 0);
    if (pf) asm volatile("s_waitcnt vmcnt(4)" ::: "memory");
    else    asm volatile("s_waitcnt vmcnt(0)" ::: "memory");
    __builtin_amdgcn_s_barrier();  // B1: cb k1 valid

    // q2 reads (cb k1, A 0-3 + B 0-3) -- hoisted above q1 MFMA
#pragma unroll
    for (int mf = 0; mf < 4; ++mf) aA[mf] = *(const bf16x8*)(&sA[cb][1][aoff[mf]]);
#pragma unroll
    for (int nf = 0; nf < 4; ++nf) bB[nf] = *(const bf16x8*)(&sB[cb][1][boff[nf]]);
    asm volatile("s_waitcnt lgkmcnt(8)" ::: "memory");
    __builtin_amdgcn_sched_barrier(0);
    __builtin_amdgcn_s_setprio(1);
#pragma unroll
    for (int mf = 0; mf < 4; ++mf)
#pragma unroll
      for (int nf = 0; nf < 4; ++nf)
        acc[4 + mf][nf] = __builtin_amdgcn_mfma_f32_16x16x32_bf16(aB[mf], bA[nf], acc[4 + mf][nf], 0, 0, 0);
    __builtin_amdgcn_s_setprio(0);
    __builtin_amdgcn_sched_barrier(0);

    // q3 reads (cb k1, A 4-7) -- hoisted above q2 MFMA
#pragma unroll
    for (int mf = 0; mf < 4; ++mf) aB[mf] = *(const bf16x8*)(&sA[cb][1][aoff[4 + mf]]);
    if (pf) stageA(nb, t + 1, 1);
    asm volatile("s_waitcnt lgkmcnt(4)" ::: "memory");
    __builtin_amdgcn_sched_barrier(0);
    __builtin_amdgcn_s_setprio(1);
#pragma unroll
    for (int mf = 0; mf < 4; ++mf)
#pragma unroll
      for (int nf = 0; nf < 4; ++nf)
        acc[mf][nf] = __builtin_amdgcn_mfma_f32_16x16x32_bf16(aA[mf], bB[nf], acc[mf][nf], 0, 0, 0);
    __builtin_amdgcn_s_setprio(0);
    __builtin_amdgcn_sched_barrier(0);

    if (pf) {
      stageB(nb, t + 1, 1);
      asm volatile("s_waitcnt vmcnt(4)" ::: "memory");
    }
    __builtin_amdgcn_s_barrier();  // B3: nb k0 valid

    // next-tile q0 reads (nb k0) -- hoisted above q3 MFMA
    if (pf) {
#pragma unroll
      for (int mf = 0; mf < 4; ++mf) aA[mf] = *(const bf16x8*)(&sA[nb][0][aoff[mf]]);
#pragma unroll
      for (int nf = 0; nf < 4; ++nf) bA[nf] = *(const bf16x8*)(&sB[nb][0][boff[nf]]);
      asm volatile("s_waitcnt lgkmcnt(8)" ::: "memory");
    } else {
      asm volatile("s_waitcnt lgkmcnt(0)" ::: "memory");
    }
    __builtin_amdgcn_sched_barrier(0);
    __builtin_amdgcn_s_setprio(1);
#pragma unroll
    for (int mf = 0; mf < 4; ++mf)
#pragma unroll
      for (int nf = 0; nf < 4; ++nf)
        acc[4 + mf][nf] = __builtin_amdgcn_mfma_f32_16x16x32_bf16(aB[mf], bB[nf], acc[4 + mf][nf], 0, 0, 0);
    __builtin_amdgcn_s_setprio(0);
    __builtin_amdgcn_sched_barrier(0);
  }

  // epilogue
#pragma unroll
  for (int mf = 0; mf < 8; ++mf) {
#pragma unroll
    for (int nf = 0; nf < 4; ++nf) {
#pragma unroll
      for (int r = 0; r < 4; ++r) {
        const int mm = m0 + wm * 128 + mf * 16 + fq * 4 + r;
        const int nn = n0 + wn * 64 + nf * 16 + fr;
        const float v = acc[mf][nf][r];
        const long cidx = (long)mm * ldc + nn;
        if constexpr (EPI == 2) {
          const float zt = sigmf(v + bias[nn]);
          const float x = (float)Xg[(long)mm * ldxy + nn];
          const float y = (float)Yg[(long)mm * ldxy + nn];
          ((__bf16*)Cout)[cidx] = (__bf16)(zt * x + (1.f - zt) * y);
        } else {
          ((__bf16*)Cout)[cidx] = (__bf16)(v + bias[nn]);
        }
      }
    }
  }
}

// ---------------------------------------------------------------------------
extern "C" void kernel_launch(void* const* d_in, const int* in_sizes, int n_in,
                              void* d_out, int out_size, void* d_ws, size_t ws_size,
                              hipStream_t stream) {
  (void)in_sizes; (void)n_in; (void)out_size;
  const float* Hs    = (const float*)d_in[0];
  const float* Hw    = (const float*)d_in[1];
  const float* HSec  = (const float*)d_in[2];
  const int* w2s     = (const int*)d_in[3];
  const int* s2s     = (const int*)d_in[4];
  const int* S2s     = (const int*)d_in[5];
  const float* Ww_src = (const float*)d_in[6];
  const float* Ww_dst = (const float*)d_in[7];
  const float* aw_src = (const float*)d_in[8];
  const float* aw_dst = (const float*)d_in[9];
  const float* bw     = (const float*)d_in[10];
  const float* Wss    = (const float*)d_in[11];
  const float* as_src = (const float*)d_in[12];
  const float* as_dst = (const float*)d_in[13];
  const float* bs     = (const float*)d_in[14];
  const float* WS_src = (const float*)d_in[15];
  const float* WS_dst = (const float*)d_in[16];
  const float* aS_src = (const float*)d_in[17];
  const float* aS_dst = (const float*)d_in[18];
  const float* bS     = (const float*)d_in[19];
  const float* F1_w   = (const float*)d_in[20];
  const float* F1_b   = (const float*)d_in[21];
  const float* F2_w   = (const float*)d_in[22];
  const float* F2_b   = (const float*)d_in[23];
  const float* l1_w   = (const float*)d_in[24];
  const float* l1_b   = (const float*)d_in[25];
  const float* l2_w   = (const float*)d_in[26];
  const float* l2_b   = (const float*)d_in[27];
  float* outp = (float*)d_out;

  char* ws = (char*)d_ws;
  size_t cur_off = 0;
  auto alloc = [&](size_t bytes) -> char* {
    char* p = ws + cur_off;
    cur_off = (cur_off + bytes + 255) & ~(size_t)255;
    return p;
  };

  __bf16* Wt_w  = (__bf16*)alloc((size_t)5120 * 320 * 2);
  __bf16* Wt_s  = (__bf16*)alloc((size_t)5120 * 640 * 2);
  __bf16* Wt_S  = (__bf16*)alloc((size_t)5120 * 512 * 2);
  __bf16* WtF   = (__bf16*)alloc((size_t)5120 * 10240 * 2);  // F1 (and F2 in fallback)
  __bf16* Wt_l2 = (__bf16*)alloc((size_t)640 * 2048 * 2);
  __bf16* l1_bf = (__bf16*)alloc((size_t)5120 * 2048 * 2);
  __bf16* WcT   = (__bf16*)alloc((size_t)640 * 5120 * 2);
  float*  bc    = (float*)alloc(640 * 4);
  __bf16* HS_bf = (__bf16*)alloc((size_t)1024 * 512 * 2);
  __bf16* Hs_bf = (__bf16*)alloc((size_t)kNS * 640 * 2);
  float* v_w = (float*)alloc(8 * 320 * 4);
  float* u_w = (float*)alloc(8 * 640 * 4);
  float* v_s = (float*)alloc(8 * 640 * 4);
  float* u_s = (float*)alloc(8 * 640 * 4);
  float* v_S = (float*)alloc(8 * 512 * 4);
  float* u_S = (float*)alloc(8 * 640 * 4);
  float* alw_s = (float*)alloc((size_t)kNW * 8 * 4);
  float* alw_d = (float*)alloc((size_t)kNS * 8 * 4);
  float* als_s = (float*)alloc((size_t)kNS * 8 * 4);
  float* als_d = (float*)alloc((size_t)kNS * 8 * 4);
  float* alS_s = (float*)alloc((size_t)kNSEC * 8 * 4);
  float* alS_d = (float*)alloc((size_t)kNS * 8 * 4);
  int* csr_i  = (int*)alloc((size_t)6 * kNS * 4);
  int* cnt_w = csr_i, *cnt_s = csr_i + kNS, *cnt_S = csr_i + 2 * kNS;
  int* cur_w = csr_i + 3 * kNS, *cur_s = csr_i + 4 * kNS, *cur_S = csr_i + 5 * kNS;
  int* off_w = (int*)alloc((size_t)(kNS + 1) * 4);
  int* off_s = (int*)alloc((size_t)(kNS + 1) * 4);
  int* off_S = (int*)alloc((size_t)(kNS + 1) * 4);
  int* ssrc_w = (int*)alloc((size_t)kEW * 4);
  int* ssrc_s = (int*)alloc((size_t)kES * 4);
  int* ssrc_S = (int*)alloc((size_t)kESEC * 4);
  __bf16* hs_Sb = (__bf16*)alloc((size_t)1024 * 5120 * 2);
  char* aggreg = alloc((size_t)kNS * 2560 * 2 + (size_t)kNS * 5120 * 2);
  __bf16* agg_w = (__bf16*)aggreg;
  __bf16* agg_s = (__bf16*)(aggreg + (size_t)kNS * 2560 * 2);
  __bf16* U1 = (__bf16*)aggreg;  // alias (agg dead by fusion1)
  __bf16* Uw = (__bf16*)alloc((size_t)kNS * 5120 * 2);
  __bf16* Us = (__bf16*)alloc((size_t)kNS * 5120 * 2);
  __bf16* US = (__bf16*)alloc((size_t)kNS * 5120 * 2);
  __bf16* U2 = Uw;  // alias (Uw dead after fusion1)

  // optional second F buffer: lets fusion1's tail blocks transpose F2
  __bf16* WtF2 = nullptr;
  {
    const size_t f2b = (size_t)5120 * 10240 * 2;
    if (cur_off + f2b + 256 <= ws_size) WtF2 = (__bf16*)alloc(f2b);
  }

  const dim3 b256(256);

  // 1) weight conversions/transposes
  conv_transpose<<<dim3(160, 5), b256, 0, stream>>>(Ww_src, 300, 5120, Wt_w, 320);
  conv_transpose<<<dim3(160, 10), b256, 0, stream>>>(Wss, 640, 5120, Wt_s, 640);
  conv_transpose<<<dim3(160, 8), b256, 0, stream>>>(WS_src, 512, 5120, Wt_S, 512);
  conv_transpose<<<dim3(160, 160), b256, 0, stream>>>(F1_w, 10240, 5120, WtF, 10240);
  conv_transpose<<<dim3(20, 32), b256, 0, stream>>>(l2_w, 2048, 640, Wt_l2, 2048);
  conv_bf<<<(1024 * 512 + 255) / 256, b256, 0, stream>>>(HSec, HS_bf, (long)1024 * 512);
  conv_bf<<<((long)kNS * 640 + 255) / 256, b256, 0, stream>>>(Hs, Hs_bf, (long)kNS * 640);
  conv_bf<<<((long)5120 * 2048 + 255) / 256, b256, 0, stream>>>(l1_w, l1_bf, (long)5120 * 2048);

  // 2) FFN collapse
  gemm_bt<5><<<dim3(40, 5, 1), b256, 0, stream>>>(
      Wt_l2, 2048, nullptr, 1 << 30, l1_bf, 2048, 2048,
      WcT, 5120, nullptr, nullptr, nullptr, 0, nullptr, 0, 0, 0, 0, 0);
  comb_bias<<<3, b256, 0, stream>>>(l1_b, l2_w, l2_b, bc);

  // 3) per-head attention vectors (6 jobs, one launch)
  {
    HVJobs jb;
    jb.j[0] = {Ww_src, aw_src, v_w, 300, 320};
    jb.j[1] = {Ww_dst, aw_dst, u_w, 640, 640};
    jb.j[2] = {Wss,    as_src, v_s, 640, 640};
    jb.j[3] = {Wss,    as_dst, u_s, 640, 640};
    jb.j[4] = {WS_src, aS_src, v_S, 512, 512};
    jb.j[5] = {WS_dst, aS_dst, u_S, 640, 640};
    head_vecs6<<<dim3(8, 160, 6), b256, 0, stream>>>(jb);
  }

  // 4) attention logits
  att_logits<<<(kNW + 3) / 4, b256, 0, stream>>>(Hw, 300, 300, v_w, 320, alw_s, kNW);
  att_logits<<<(kNSEC + 3) / 4, b256, 0, stream>>>(HSec, 512, 512, v_S, 512, alS_s, kNSEC);
  att_logits4<<<(kNS + 3) / 4, b256, 0, stream>>>(Hs, u_w, v_s, u_s, u_S,
                                                  alw_d, als_s, als_d, alS_d, kNS);

  // 5) CSR build (merged launches)
  hipMemsetAsync(csr_i, 0, (size_t)6 * kNS * 4, stream);
  edge_count3<<<(kEW + kES + kESEC + 255) / 256, b256, 0, stream>>>(
      w2s + kEW, kEW, cnt_w, s2s + kES, kES, cnt_s, S2s + kESEC, kESEC, cnt_S);
  scan_off3<<<3, 1024, 0, stream>>>(cnt_w, off_w, cnt_s, off_s, cnt_S, off_S);
  edge_fill3<<<(kEW + kES + kESEC + 255) / 256, b256, 0, stream>>>(
      w2s, w2s + kEW, kEW, off_w, cur_w, ssrc_w,
      s2s, s2s + kES, kES, off_s, cur_s, ssrc_s,
      S2s, S2s + kESEC, kESEC, off_S, cur_S, ssrc_S);

  // 6) section source transform: hs_Sb = HS @ WS_src  (bf16 out)
  gemm_bt<5><<<dim3(40, 8, 1), b256, 0, stream>>>(
      HS_bf, 512, nullptr, 1 << 30, Wt_S, 512, 512,
      hs_Sb, 5120, nullptr, nullptr, nullptr, 0, nullptr, 0, 0, 0, 0, 0);

  // 7) aggregations (w: f32/float4; s,S: bf16/bf16x8)
  gat_agg<320, 300, false, false><<<kNS, b256, 0, stream>>>(off_w, ssrc_w, alw_s, alw_d, Hw, 300, agg_w, 2560, nullptr);
  gat_agg_bf<640, 640, false, false><<<kNS, b256, 0, stream>>>(off_s, ssrc_s, als_s, als_d, Hs_bf, 640, agg_s, 5120, nullptr);
  gat_agg_bf<640, 640, true, true><<<kNS, b256, 0, stream>>>(off_S, ssrc_S, alS_s, alS_d, hs_Sb, 5120, US, 5120, bS);

  // 8) per-head GAT output GEMMs (+bias +ELU)
  gemm_bt<1><<<dim3(5, 64, 8), b256, 0, stream>>>(
      agg_w, 2560, nullptr, 1 << 30, Wt_w, 320, 320,
      Uw, 5120, bw, nullptr, nullptr, 0, nullptr, 0, 320, (long)640 * 320, 640, 640);
  gemm_bt<1><<<dim3(5, 64, 8), b256, 0, stream>>>(
      agg_s, 5120, nullptr, 1 << 30, Wt_s, 640, 640,
      Us, 5120, bs, nullptr, nullptr, 0, nullptr, 0, 640, (long)640 * 640, 640, 640);

  // 9) fusion 1: U1 = z*Uw + (1-z)*Us   (+F2 transpose riding the tail round)
  if (WtF2) {
    gemm256<2><<<dim3(640 + 128), dim3(512), 0, stream>>>(
        Uw, 5120, Us, 5120, WtF, 10240, 10240,
        U1, 5120, F1_b, Uw, Us, 5120, 20,
        640, F2_w, WtF2, 10240, 5120, 10240);
  } else {
    gemm256<2><<<dim3(640), dim3(512), 0, stream>>>(
        Uw, 5120, Us, 5120, WtF, 10240, 10240,
        U1, 5120, F1_b, Uw, Us, 5120, 20,
        640, nullptr, nullptr, 0, 0, 0);
    conv_transpose<<<dim3(160, 160), b256, 0, stream>>>(F2_w, 10240, 5120, WtF, 10240);
  }

  // 10) fusion 2 -> U2
  gemm256<2><<<dim3(640), dim3(512), 0, stream>>>(
      U1, 5120, US, 5120, WtF2 ? WtF2 : WtF, 10240, 10240,
      U2, 5120, F2_b, U1, US, 5120, 20,
      640, nullptr, nullptr, 0, 0, 0);

  // 11) collapsed FFN: out = U2 @ Wc + bc + Hs
  gemm_bt<4><<<dim3(5, 64, 1), b256, 0, stream>>>(
      U2, 5120, nullptr, 1 << 30, WcT, 5120, 5120,
      outp, 640, bc, nullptr, nullptr, 0, Hs, 640, 0, 0, 0, 0);
}

// Round 9
// 3088.263 us; speedup vs baseline: 1.0006x; 1.0006x over previous
//
#include <hip/hip_runtime.h>
#include <cstdint>
#include <cstddef>

typedef __attribute__((ext_vector_type(8))) __bf16 bf16x8;
typedef __attribute__((ext_vector_type(4))) float f32x4;
typedef __attribute__((ext_vector_type(16))) float f32x16;

static constexpr int kNS   = 8192;
static constexpr int kNW   = 65536;
static constexpr int kNSEC = 1024;
static constexpr int kEW   = 131072;
static constexpr int kES   = 262144;
static constexpr int kESEC = 16384;

__device__ __forceinline__ float eluf(float x)  { return x > 0.f ? x : (__expf(x) - 1.f); }
__device__ __forceinline__ float sigmf(float x) { return 1.f / (1.f + __expf(-x)); }

// async global -> LDS, 16 bytes per lane (dest must be linear in lane order)
__device__ __forceinline__ void gload16(const __bf16* g, __bf16* l) {
  __builtin_amdgcn_global_load_lds((const __attribute__((address_space(1))) unsigned int*)g,
                                   (__attribute__((address_space(3))) unsigned int*)l,
                                   16, 0, 0);
}

// ---------------------------------------------------------------------------
// Weight convert + transpose: W[K][N] f32 -> Wt[N][KP] bf16 (zero-pad k>=K)
// ---------------------------------------------------------------------------
__global__ __launch_bounds__(256) void conv_transpose(const float* __restrict__ W, int K, int N,
                                                      __bf16* __restrict__ Wt, int KP) {
  __shared__ float t[64][33];
  const int nb = blockIdx.x * 32, kb = blockIdx.y * 64;
  const int tx = threadIdx.x & 31, ty = threadIdx.x >> 5;
#pragma unroll
  for (int i = ty; i < 64; i += 8) {
    const int k = kb + i;
    t[i][tx] = (k < K) ? W[(long)k * N + nb + tx] : 0.f;
  }
  __syncthreads();
  union BU { __bf16 b; unsigned short u; };
#pragma unroll
  for (int i = ty; i < 32; i += 8) {
    BU b0, b1;
    b0.b = (__bf16)t[tx * 2][i];
    b1.b = (__bf16)t[tx * 2 + 1][i];
    const unsigned int pk = ((unsigned int)b1.u << 16) | b0.u;
    *(unsigned int*)(Wt + (long)(nb + i) * KP + kb + tx * 2) = pk;
  }
}

__global__ __launch_bounds__(256) void conv_bf(const float* __restrict__ in, __bf16* __restrict__ outb, long n) {
  long i = (long)blockIdx.x * blockDim.x + threadIdx.x;
  if (i < n) outb[i] = (__bf16)in[i];
}

// ---------------------------------------------------------------------------
// Head vectors, 6 jobs in one launch
// ---------------------------------------------------------------------------
struct HVJ { const float* W; const float* a; float* o; int Kd; int KP; };
struct HVJobs { HVJ j[6]; };

__global__ __launch_bounds__(256) void head_vecs6(HVJobs jb) {
  const HVJ J = jb.j[blockIdx.z];
  const int h = blockIdx.x;
  const int lane = threadIdx.x & 63;
  const int k = blockIdx.y * 4 + (threadIdx.x >> 6);
  if (k >= J.KP) return;
  float s = 0.f;
  if (k < J.Kd) {
    const float* wr = J.W + (long)k * 5120 + h * 640;
    const float* ar = J.a + h * 640;
    for (int c = lane; c < 640; c += 64) s += wr[c] * ar[c];
  }
  for (int o2 = 32; o2; o2 >>= 1) s += __shfl_down(s, o2);
  if (lane == 0) J.o[h * J.KP + k] = (k < J.Kd) ? s : 0.f;
}

// Combined FFN bias: bc[n] = sum_k l1_b[k]*l2_w[k][n] + l2_b[n]
__global__ __launch_bounds__(256) void comb_bias(const float* __restrict__ l1_b, const float* __restrict__ l2_w,
                                                 const float* __restrict__ l2_b, float* __restrict__ bc) {
  const int n = blockIdx.x * 256 + threadIdx.x;
  if (n >= 640) return;
  float s = l2_b[n];
  for (int k = 0; k < 2048; ++k) s += l1_b[k] * l2_w[(long)k * 640 + n];
  bc[n] = s;
}

// ---------------------------------------------------------------------------
// Attention logits
// ---------------------------------------------------------------------------
__global__ __launch_bounds__(256) void att_logits(const float* __restrict__ X, int ldx, int Kd,
                                                  const float* __restrict__ vec, int KP,
                                                  float* __restrict__ outl, int N) {
  const int lane = threadIdx.x & 63;
  const int node = blockIdx.x * 4 + (threadIdx.x >> 6);
  if (node >= N) return;
  const float* xr = X + (long)node * ldx;
  float p[8];
#pragma unroll
  for (int h = 0; h < 8; ++h) p[h] = 0.f;
  for (int k = lane; k < Kd; k += 64) {
    const float xv = xr[k];
#pragma unroll
    for (int h = 0; h < 8; ++h) p[h] += xv * vec[h * KP + k];
  }
#pragma unroll
  for (int h = 0; h < 8; ++h) {
    float v = p[h];
    for (int o2 = 32; o2; o2 >>= 1) v += __shfl_down(v, o2);
    if (lane == 0) outl[(long)node * 8 + h] = v;
  }
}

__global__ __launch_bounds__(256) void att_logits4(const float* __restrict__ X,
                                                   const float* __restrict__ v0, const float* __restrict__ v1,
                                                   const float* __restrict__ v2, const float* __restrict__ v3,
                                                   float* __restrict__ o0, float* __restrict__ o1,
                                                   float* __restrict__ o2, float* __restrict__ o3, int N) {
  const int lane = threadIdx.x & 63;
  const int node = blockIdx.x * 4 + (threadIdx.x >> 6);
  if (node >= N) return;
  const float* xr = X + (long)node * 640;
  float p[4][8];
#pragma unroll
  for (int s = 0; s < 4; ++s)
#pragma unroll
    for (int h = 0; h < 8; ++h) p[s][h] = 0.f;
  for (int k = lane; k < 640; k += 64) {
    const float xv = xr[k];
#pragma unroll
    for (int h = 0; h < 8; ++h) {
      p[0][h] += xv * v0[h * 640 + k];
      p[1][h] += xv * v1[h * 640 + k];
      p[2][h] += xv * v2[h * 640 + k];
      p[3][h] += xv * v3[h * 640 + k];
    }
  }
  float* outs[4] = {o0, o1, o2, o3};
#pragma unroll
  for (int s = 0; s < 4; ++s)
#pragma unroll
    for (int h = 0; h < 8; ++h) {
      float v = p[s][h];
      for (int o2v = 32; o2v; o2v >>= 1) v += __shfl_down(v, o2v);
      if (lane == 0) outs[s][(long)node * 8 + h] = v;
    }
}

// ---------------------------------------------------------------------------
// CSR build (3 edge lists per launch)
// ---------------------------------------------------------------------------
__global__ __launch_bounds__(256) void edge_count3(const int* __restrict__ d0, int E0, int* __restrict__ c0,
                                                   const int* __restrict__ d1, int E1, int* __restrict__ c1,
                                                   const int* __restrict__ d2, int E2, int* __restrict__ c2) {
  const int gid = blockIdx.x * blockDim.x + threadIdx.x;
  if (gid < E0) atomicAdd(&c0[d0[gid]], 1);
  else if (gid < E0 + E1) atomicAdd(&c1[d1[gid - E0]], 1);
  else if (gid < E0 + E1 + E2) atomicAdd(&c2[d2[gid - E0 - E1]], 1);
}

__global__ __launch_bounds__(1024) void scan_off3(const int* __restrict__ c0, int* __restrict__ o0,
                                                  const int* __restrict__ c1, int* __restrict__ o1,
                                                  const int* __restrict__ c2, int* __restrict__ o2) {
  const int* cnt = blockIdx.x == 0 ? c0 : (blockIdx.x == 1 ? c1 : c2);
  int* offo = blockIdx.x == 0 ? o0 : (blockIdx.x == 1 ? o1 : o2);
  __shared__ int part[1024];
  const int tid = threadIdx.x;
  const int base = tid * 8;
  int loc[8];
  int s = 0;
#pragma unroll
  for (int i = 0; i < 8; ++i) { loc[i] = s; s += cnt[base + i]; }
  part[tid] = s;
  __syncthreads();
  for (int d2 = 1; d2 < 1024; d2 <<= 1) {
    int v = (tid >= d2) ? part[tid - d2] : 0;
    __syncthreads();
    part[tid] += v;
    __syncthreads();
  }
  const int pre = (tid > 0) ? part[tid - 1] : 0;
#pragma unroll
  for (int i = 0; i < 8; ++i) offo[base + i] = pre + loc[i];
  if (tid == 1023) offo[8192] = part[1023];
}

__global__ __launch_bounds__(256) void edge_fill3(
    const int* __restrict__ s0, const int* __restrict__ d0, int E0, const int* __restrict__ of0, int* __restrict__ cu0, int* __restrict__ sr0,
    const int* __restrict__ s1, const int* __restrict__ d1, int E1, const int* __restrict__ of1, int* __restrict__ cu1, int* __restrict__ sr1,
    const int* __restrict__ s2, const int* __restrict__ d2, int E2, const int* __restrict__ of2, int* __restrict__ cu2, int* __restrict__ sr2) {
  const int gid = blockIdx.x * blockDim.x + threadIdx.x;
  if (gid < E0) {
    const int d = d0[gid];
    sr0[of0[d] + atomicAdd(&cu0[d], 1)] = s0[gid];
  } else if (gid < E0 + E1) {
    const int g = gid - E0, d = d1[g];
    sr1[of1[d] + atomicAdd(&cu1[d], 1)] = s1[g];
  } else if (gid < E0 + E1 + E2) {
    const int g = gid - E0 - E1, d = d2[g];
    sr2[of2[d] + atomicAdd(&cu2[d], 1)] = s2[g];
  }
}

// ---------------------------------------------------------------------------
// GAT aggregation, f32 X (float4) -- word layer (F=300)
// ---------------------------------------------------------------------------
template <int FPAD, int F, bool XPH, bool BIASELU>
__global__ __launch_bounds__(256) void gat_agg(const int* __restrict__ seg_off, const int* __restrict__ ssrc,
                                               const float* __restrict__ als, const float* __restrict__ ald,
                                               const float* __restrict__ X, int ldx,
                                               __bf16* __restrict__ outp, int ldo,
                                               const float* __restrict__ bias) {
  constexpr int C4 = F / 4;
  constexpr int ITEMS = 8 * C4;
  constexpr int L = (ITEMS + 255) / 256;
  const int d = blockIdx.x;
  const int tid = threadIdx.x;
  const int o0 = seg_off[d], o1 = seg_off[d + 1];
  const int deg = o1 - o0;
  __shared__ float exl[64][8];
  __shared__ int ssl[64];
  __shared__ float aldd[8];
  __shared__ float den_s[8];
  if (tid < 8) { aldd[tid] = ald[(long)d * 8 + tid]; den_s[tid] = 0.f; }
  f32x4 acc[L];
  int hh[L], xo[L], oo[L];
  bool vld[L];
#pragma unroll
  for (int l = 0; l < L; ++l) {
    const int idx = tid + l * 256;
    vld[l] = (idx < ITEMS);
    const int h = vld[l] ? (idx / C4) : 0;
    const int c = vld[l] ? (idx - h * C4) : 0;
    hh[l] = h;
    xo[l] = (XPH ? h * F : 0) + c * 4;
    oo[l] = h * FPAD + c * 4;
#pragma unroll
    for (int r = 0; r < 4; ++r) acc[l][r] = 0.f;
  }
  __syncthreads();
  for (int base = 0; base < deg; base += 64) {
    const int nc = min(64, deg - base);
    if (tid < nc) ssl[tid] = ssrc[o0 + base + tid];
    __syncthreads();
    for (int t = tid; t < nc * 8; t += 256) {
      const int e = t >> 3, h = t & 7;
      float v = als[(long)ssl[e] * 8 + h] + aldd[h];
      v = v > 0.f ? v : 0.2f * v;
      exl[e][h] = __expf(v);
    }
    __syncthreads();
    if (tid < 8) {
      float s = 0.f;
      for (int e = 0; e < nc; ++e) s += exl[e][tid];
      den_s[tid] += s;
    }
    for (int e = 0; e < nc; ++e) {
      const float* xr = X + (long)ssl[e] * ldx;
      const float* ex8 = exl[e];
#pragma unroll
      for (int l = 0; l < L; ++l)
        if (vld[l]) {
          const f32x4 v = *(const f32x4*)(xr + xo[l]);
          acc[l] += ex8[hh[l]] * v;
        }
    }
    __syncthreads();
  }
#pragma unroll
  for (int l = 0; l < L; ++l) {
    if (!vld[l]) continue;
    const float dinv = 1.f / (den_s[hh[l]] + 1e-16f);
#pragma unroll
    for (int j = 0; j < 4; ++j) {
      float r = acc[l][j] * dinv;
      if constexpr (BIASELU) { r += bias[oo[l] + j]; r = eluf(r); }
      outp[(long)d * ldo + oo[l] + j] = (__bf16)r;
    }
  }
}

// ---------------------------------------------------------------------------
// GAT aggregation, bf16 X (bf16x8) -- sentence & section layers
// ---------------------------------------------------------------------------
template <int FPAD, int F, bool XPH, bool BIASELU>
__global__ __launch_bounds__(256) void gat_agg_bf(const int* __restrict__ seg_off, const int* __restrict__ ssrc,
                                                  const float* __restrict__ als, const float* __restrict__ ald,
                                                  const __bf16* __restrict__ X, int ldx,
                                                  __bf16* __restrict__ outp, int ldo,
                                                  const float* __restrict__ bias) {
  constexpr int C8 = F / 8;
  constexpr int ITEMS = 8 * C8;
  constexpr int L = (ITEMS + 255) / 256;
  const int d = blockIdx.x;
  const int tid = threadIdx.x;
  const int o0 = seg_off[d], o1 = seg_off[d + 1];
  const int deg = o1 - o0;
  __shared__ float exl[64][8];
  __shared__ int ssl[64];
  __shared__ float aldd[8];
  __shared__ float den_s[8];
  if (tid < 8) { aldd[tid] = ald[(long)d * 8 + tid]; den_s[tid] = 0.f; }
  float acc[L][8];
  int hh[L], xo[L], oo[L];
  bool vld[L];
#pragma unroll
  for (int l = 0; l < L; ++l) {
    const int idx = tid + l * 256;
    vld[l] = (idx < ITEMS);
    const int h = vld[l] ? (idx / C8) : 0;
    const int c = vld[l] ? (idx - h * C8) : 0;
    hh[l] = h;
    xo[l] = (XPH ? h * F : 0) + c * 8;
    oo[l] = h * FPAD + c * 8;
#pragma unroll
    for (int r = 0; r < 8; ++r) acc[l][r] = 0.f;
  }
  __syncthreads();
  for (int base = 0; base < deg; base += 64) {
    const int nc = min(64, deg - base);
    if (tid < nc) ssl[tid] = ssrc[o0 + base + tid];
    __syncthreads();
    for (int t = tid; t < nc * 8; t += 256) {
      const int e = t >> 3, h = t & 7;
      float v = als[(long)ssl[e] * 8 + h] + aldd[h];
      v = v > 0.f ? v : 0.2f * v;
      exl[e][h] = __expf(v);
    }
    __syncthreads();
    if (tid < 8) {
      float s = 0.f;
      for (int e = 0; e < nc; ++e) s += exl[e][tid];
      den_s[tid] += s;
    }
    for (int e = 0; e < nc; ++e) {
      const __bf16* xr = X + (long)ssl[e] * ldx;
      const float* ex8 = exl[e];
#pragma unroll
      for (int l = 0; l < L; ++l)
        if (vld[l]) {
          const bf16x8 v = *(const bf16x8*)(xr + xo[l]);
          const float w = ex8[hh[l]];
#pragma unroll
          for (int r = 0; r < 8; ++r) acc[l][r] += w * (float)v[r];
        }
    }
    __syncthreads();
  }
#pragma unroll
  for (int l = 0; l < L; ++l) {
    if (!vld[l]) continue;
    const float dinv = 1.f / (den_s[hh[l]] + 1e-16f);
#pragma unroll
    for (int j = 0; j < 8; ++j) {
      float r = acc[l][j] * dinv;
      if constexpr (BIASELU) { r += bias[oo[l] + j]; r = eluf(r); }
      outp[(long)d * ldo + oo[l] + j] = (__bf16)r;
    }
  }
}

// ---------------------------------------------------------------------------
// 128x128-tile MFMA GEMM (m97-class, 2-barrier) -- small/batched GEMMs.
// EPI: 0 store f32 | 1 bias+ELU->bf16 | 2 sigmoid-gate mix->bf16
//      3 bias->bf16 | 4 bias+residual->f32 | 5 store bf16
// ---------------------------------------------------------------------------
template <int EPI>
__global__ __launch_bounds__(256) void gemm_bt(
    const __bf16* __restrict__ A, int lda, const __bf16* __restrict__ A2, int ksplit,
    const __bf16* __restrict__ Bt, int ldb, int K,
    void* __restrict__ Cout, int ldc,
    const float* __restrict__ bias,
    const __bf16* __restrict__ Xg, const __bf16* __restrict__ Yg, int ldxy,
    const float* __restrict__ Res, int ldres,
    long a_zs, long bt_zs, long c_zs, int b_zs) {
  __shared__ __bf16 sA[2][128 * 32];
  __shared__ __bf16 sB[2][128 * 32];
  const int tid = threadIdx.x;
  const int z = blockIdx.z;
  const int m0 = blockIdx.y * 128, n0 = blockIdx.x * 128;
  const __bf16* Ab = A + (long)z * a_zs;
  const __bf16* A2b = A2 ? A2 + (long)z * a_zs : nullptr;
  const __bf16* Btb = Bt + (long)z * bt_zs;
  const int lane = tid & 63;
  const int wv = tid >> 6, wr = wv >> 1, wc = wv & 1;
  const int fr = lane & 15, fq = lane >> 4;

  const int r0 = tid >> 2, r1 = r0 + 64;
  const int csw = (((tid & 3) ^ ((r0 >> 1) & 3)) * 8);
  const int ldst0 = tid * 8;
  const int ldst1 = 2048 + tid * 8;

  f32x4 acc[4][4];
#pragma unroll
  for (int i = 0; i < 4; ++i)
#pragma unroll
    for (int j = 0; j < 4; ++j)
#pragma unroll
      for (int r = 0; r < 4; ++r) acc[i][j][r] = 0.f;

  const int fsw = (fq ^ ((fr >> 1) & 3)) * 8;
  int aof[4], bof[4];
#pragma unroll
  for (int i = 0; i < 4; ++i) {
    aof[i] = (wr * 64 + i * 16 + fr) * 32 + fsw;
    bof[i] = (wc * 64 + i * 16 + fr) * 32 + fsw;
  }

  const int nkt = K >> 5;
  auto stage = [&](int buf, int kt) {
    const int k0 = kt * 32;
    const __bf16* As = Ab;
    int kr = k0;
    if (A2b && k0 >= ksplit) { As = A2b; kr = k0 - ksplit; }
    gload16(As + (long)(m0 + r0) * lda + kr + csw, &sA[buf][ldst0]);
    gload16(As + (long)(m0 + r1) * lda + kr + csw, &sA[buf][ldst1]);
    gload16(Btb + (long)(n0 + r0) * ldb + k0 + csw, &sB[buf][ldst0]);
    gload16(Btb + (long)(n0 + r1) * ldb + k0 + csw, &sB[buf][ldst1]);
  };

  stage(0, 0);
  for (int kt = 0; kt < nkt; ++kt) {
    const int cur = kt & 1;
    __syncthreads();
    if (kt + 1 < nkt) stage(cur ^ 1, kt + 1);
    bf16x8 af[4], bfv[4];
#pragma unroll
    for (int i = 0; i < 4; ++i) {
      af[i] = *(const bf16x8*)(&sA[cur][aof[i]]);
      bfv[i] = *(const bf16x8*)(&sB[cur][bof[i]]);
    }
#pragma unroll
    for (int i = 0; i < 4; ++i)
#pragma unroll
      for (int j = 0; j < 4; ++j)
        acc[i][j] = __builtin_amdgcn_mfma_f32_16x16x32_bf16(af[i], bfv[j], acc[i][j], 0, 0, 0);
  }

  const float* biasb = bias ? bias + (long)z * b_zs : nullptr;
#pragma unroll
  for (int i = 0; i < 4; ++i) {
#pragma unroll
    for (int j = 0; j < 4; ++j) {
#pragma unroll
      for (int r = 0; r < 4; ++r) {
        const int mm = m0 + wr * 64 + i * 16 + fq * 4 + r;
        const int nn = n0 + wc * 64 + j * 16 + fr;
        const float v = acc[i][j][r];
        const long cidx = (long)mm * ldc + nn + (long)z * c_zs;
        if constexpr (EPI == 0) {
          ((float*)Cout)[cidx] = v;
        } else if constexpr (EPI == 1) {
          ((__bf16*)Cout)[cidx] = (__bf16)eluf(v + biasb[nn]);
        } else if constexpr (EPI == 2) {
          const float zt = sigmf(v + biasb[nn]);
          const float x = (float)Xg[(long)mm * ldxy + nn];
          const float y = (float)Yg[(long)mm * ldxy + nn];
          ((__bf16*)Cout)[cidx] = (__bf16)(zt * x + (1.f - zt) * y);
        } else if constexpr (EPI == 3) {
          ((__bf16*)Cout)[cidx] = (__bf16)(v + biasb[nn]);
        } else if constexpr (EPI == 4) {
          ((float*)Cout)[cidx] = v + biasb[nn] + Res[(long)mm * ldres + nn];
        } else {
          ((__bf16*)Cout)[cidx] = (__bf16)v;
        }
      }
    }
  }
}

// ---------------------------------------------------------------------------
// 256x256-tile 8-wave MFMA GEMM, hoisted-reads pipeline (R7 schedule),
// now on v_mfma_f32_32x32x16_bf16 (higher MFMA-pipe ceiling, same LDS
// traffic, same barrier/vmcnt/lgkmcnt ledger).
// Per wave: 128x64 output = 4 Mfrags x 2 Nfrags of 32x32 (f32x16 acc).
// A-frag (mf, kstep s): row = wm*128+mf*32+(lane&31),
//   k-slot = s*2+(lane>>5), XOR-swizzled with (row>>1)&3.
// C/D layout (m74/m101): col = lane&31, row = (r&3)+8*(r>>2)+4*(lane>>5).
// EPI: 2 sigmoid-gate mix->bf16 | 3 bias->bf16
// ---------------------------------------------------------------------------
template <int EPI>
__global__ __launch_bounds__(512, 2) void gemm256(
    const __bf16* __restrict__ A, int lda, const __bf16* __restrict__ A2, int ksplit,
    const __bf16* __restrict__ Bt, int ldb, int K,
    void* __restrict__ Cout, int ldc,
    const float* __restrict__ bias,
    const __bf16* __restrict__ Xg, const __bf16* __restrict__ Yg, int ldxy,
    int nn_tiles) {
  __shared__ __bf16 sA[2][2][256 * 32];
  __shared__ __bf16 sB[2][2][256 * 32];
  const int tid = threadIdx.x;

  const int nwg = gridDim.x;
  const int lin = blockIdx.x;
  const int qq = nwg >> 3, rr = nwg & 7;
  const int xcd = lin & 7, pos = lin >> 3;
  const int swz = (xcd < rr ? xcd * (qq + 1) : rr * (qq + 1) + (xcd - rr) * qq) + pos;
  const int m0 = (swz / nn_tiles) * 256;
  const int n0 = (swz % nn_tiles) * 256;

  const int lane = tid & 63;
  const int wv = tid >> 6, wm = wv >> 2, wn = wv & 3;
  const int lr = lane & 31;   // row within 32-frag
  const int l5 = lane >> 5;   // k-group

  const int srow = tid >> 2;
  const int pslot = tid & 3;

  auto stageA = [&](int bp, int tt, int kk) {
    const int kcol0 = tt * 64 + kk * 32;
    const __bf16* src = A;
    int kc = kcol0;
    if (A2 && kcol0 >= ksplit) { src = A2; kc = kcol0 - ksplit; }
    __bf16* dst = &sA[bp][kk][0];
#pragma unroll
    for (int i = 0; i < 2; ++i) {
      const int r = i * 128 + srow;
      const int l = pslot ^ ((r >> 1) & 3);
      gload16(src + (long)(m0 + r) * lda + kc + l * 8, dst + (i * 512 + tid) * 8);
    }
  };
  auto stageB = [&](int bp, int tt, int kk) {
    const int kcol0 = tt * 64 + kk * 32;
    __bf16* dst = &sB[bp][kk][0];
#pragma unroll
    for (int i = 0; i < 2; ++i) {
      const int r = i * 128 + srow;
      const int l = pslot ^ ((r >> 1) & 3);
      gload16(Bt + (long)(n0 + r) * ldb + kcol0 + l * 8, dst + (i * 512 + tid) * 8);
    }
  };

  // frag offsets: A mf 0..3, B nf 0..1; kstep s 0..1 within a 32-wide kk slice
  int aoff[4][2], boff[2][2];
#pragma unroll
  for (int mf = 0; mf < 4; ++mf) {
#pragma unroll
    for (int s = 0; s < 2; ++s) {
      const int ra = wm * 128 + mf * 32 + lr;
      aoff[mf][s] = ra * 32 + (((s * 2 + l5) ^ ((ra >> 1) & 3)) * 8);
    }
  }
#pragma unroll
  for (int nf = 0; nf < 2; ++nf) {
#pragma unroll
    for (int s = 0; s < 2; ++s) {
      const int rb = wn * 64 + nf * 32 + lr;
      boff[nf][s] = rb * 32 + (((s * 2 + l5) ^ ((rb >> 1) & 3)) * 8);
    }
  }

  f32x16 acc[4][2];
#pragma unroll
  for (int i = 0; i < 4; ++i)
#pragma unroll
    for (int j = 0; j < 2; ++j)
#pragma unroll
      for (int r = 0; r < 16; ++r) acc[i][j][r] = 0.f;

  const int nkt = K >> 6;

  bf16x8 aA[2][2], aB[2][2], bA[2][2], bB[2][2];

  // prologue: stage tile 0; k0 halves ready; pre-read q0 frags
  stageA(0, 0, 0); stageB(0, 0, 0); stageA(0, 0, 1); stageB(0, 0, 1);
  asm volatile("s_waitcnt vmcnt(4)" ::: "memory");
  __builtin_amdgcn_s_barrier();
#pragma unroll
  for (int m = 0; m < 2; ++m)
#pragma unroll
    for (int s = 0; s < 2; ++s) aA[m][s] = *(const bf16x8*)(&sA[0][0][aoff[m][s]]);
#pragma unroll
  for (int n = 0; n < 2; ++n)
#pragma unroll
    for (int s = 0; s < 2; ++s) bA[n][s] = *(const bf16x8*)(&sB[0][0][boff[n][s]]);

  for (int t = 0; t < nkt; ++t) {
    const int cb = t & 1, nb = cb ^ 1;
    const bool pf = (t + 1 < nkt);

    // q1 reads (cb k0, Mfrags 2-3) -- hoisted above q0 MFMA
#pragma unroll
    for (int m = 0; m < 2; ++m)
#pragma unroll
      for (int s = 0; s < 2; ++s) aB[m][s] = *(const bf16x8*)(&sA[cb][0][aoff[2 + m][s]]);
    if (pf) stageA(nb, t + 1, 0);
    asm volatile("s_waitcnt lgkmcnt(4)" ::: "memory");  // aA,bA done (aB in flight)
    __builtin_amdgcn_sched_barrier(0);
    __builtin_amdgcn_s_setprio(1);
#pragma unroll
    for (int m = 0; m < 2; ++m)
#pragma unroll
      for (int n = 0; n < 2; ++n)
#pragma unroll
        for (int s = 0; s < 2; ++s)
          acc[m][n] = __builtin_amdgcn_mfma_f32_32x32x16_bf16(aA[m][s], bA[n][s], acc[m][n], 0, 0, 0);
    __builtin_amdgcn_s_setprio(0);
    __builtin_amdgcn_sched_barrier(0);

    if (pf) stageB(nb, t + 1, 0);
    if (pf) asm volatile("s_waitcnt vmcnt(4)" ::: "memory");  // drains cb k1
    else    asm volatile("s_waitcnt vmcnt(0)" ::: "memory");
    __builtin_amdgcn_s_barrier();  // B1: cb k1 valid

    // q2 reads (cb k1, Mfrags 0-1 + B) -- hoisted above q1 MFMA
#pragma unroll
    for (int m = 0; m < 2; ++m)
#pragma unroll
      for (int s = 0; s < 2; ++s) aA[m][s] = *(const bf16x8*)(&sA[cb][1][aoff[m][s]]);
#pragma unroll
    for (int n = 0; n < 2; ++n)
#pragma unroll
      for (int s = 0; s < 2; ++s) bB[n][s] = *(const bf16x8*)(&sB[cb][1][boff[n][s]]);
    asm volatile("s_waitcnt lgkmcnt(8)" ::: "memory");  // aB done
    __builtin_amdgcn_sched_barrier(0);
    __builtin_amdgcn_s_setprio(1);
#pragma unroll
    for (int m = 0; m < 2; ++m)
#pragma unroll
      for (int n = 0; n < 2; ++n)
#pragma unroll
        for (int s = 0; s < 2; ++s)
          acc[2 + m][n] = __builtin_amdgcn_mfma_f32_32x32x16_bf16(aB[m][s], bA[n][s], acc[2 + m][n], 0, 0, 0);
    __builtin_amdgcn_s_setprio(0);
    __builtin_amdgcn_sched_barrier(0);

    // q3 reads (cb k1, Mfrags 2-3) -- hoisted above q2 MFMA
#pragma unroll
    for (int m = 0; m < 2; ++m)
#pragma unroll
      for (int s = 0; s < 2; ++s) aB[m][s] = *(const bf16x8*)(&sA[cb][1][aoff[2 + m][s]]);
    if (pf) stageA(nb, t + 1, 1);
    asm volatile("s_waitcnt lgkmcnt(4)" ::: "memory");  // aA,bB done
    __builtin_amdgcn_sched_barrier(0);
    __builtin_amdgcn_s_setprio(1);
#pragma unroll
    for (int m = 0; m < 2; ++m)
#pragma unroll
      for (int n = 0; n < 2; ++n)
#pragma unroll
        for (int s = 0; s < 2; ++s)
          acc[m][n] = __builtin_amdgcn_mfma_f32_32x32x16_bf16(aA[m][s], bB[n][s], acc[m][n], 0, 0, 0);
    __builtin_amdgcn_s_setprio(0);
    __builtin_amdgcn_sched_barrier(0);

    if (pf) {
      stageB(nb, t + 1, 1);
      asm volatile("s_waitcnt vmcnt(4)" ::: "memory");  // drains nb k0
    }
    __builtin_amdgcn_s_barrier();  // B3: nb k0 valid

    // next-tile q0 reads (nb k0) -- hoisted above q3 MFMA
    if (pf) {
#pragma unroll
      for (int m = 0; m < 2; ++m)
#pragma unroll
        for (int s = 0; s < 2; ++s) aA[m][s] = *(const bf16x8*)(&sA[nb][0][aoff[m][s]]);
#pragma unroll
      for (int n = 0; n < 2; ++n)
#pragma unroll
        for (int s = 0; s < 2; ++s) bA[n][s] = *(const bf16x8*)(&sB[nb][0][boff[n][s]]);
      asm volatile("s_waitcnt lgkmcnt(8)" ::: "memory");  // aB done
    } else {
      asm volatile("s_waitcnt lgkmcnt(0)" ::: "memory");
    }
    __builtin_amdgcn_sched_barrier(0);
    __builtin_amdgcn_s_setprio(1);
#pragma unroll
    for (int m = 0; m < 2; ++m)
#pragma unroll
      for (int n = 0; n < 2; ++n)
#pragma unroll
        for (int s = 0; s < 2; ++s)
          acc[2 + m][n] = __builtin_amdgcn_mfma_f32_32x32x16_bf16(aB[m][s], bB[n][s], acc[2 + m][n], 0, 0, 0);
    __builtin_amdgcn_s_setprio(0);
    __builtin_amdgcn_sched_barrier(0);
  }

  // epilogue: C/D 32x32 mapping (col=lane&31, row=(r&3)+8*(r>>2)+4*l5)
#pragma unroll
  for (int mf = 0; mf < 4; ++mf) {
#pragma unroll
    for (int nf = 0; nf < 2; ++nf) {
#pragma unroll
      for (int r = 0; r < 16; ++r) {
        const int mm = m0 + wm * 128 + mf * 32 + (r & 3) + 8 * (r >> 2) + 4 * l5;
        const int nn = n0 + wn * 64 + nf * 32 + lr;
        const float v = acc[mf][nf][r];
        const long cidx = (long)mm * ldc + nn;
        if constexpr (EPI == 2) {
          const float zt = sigmf(v + bias[nn]);
          const float x = (float)Xg[(long)mm * ldxy + nn];
          const float y = (float)Yg[(long)mm * ldxy + nn];
          ((__bf16*)Cout)[cidx] = (__bf16)(zt * x + (1.f - zt) * y);
        } else {
          ((__bf16*)Cout)[cidx] = (__bf16)(v + bias[nn]);
        }
      }
    }
  }
}

// ---------------------------------------------------------------------------
extern "C" void kernel_launch(void* const* d_in, const int* in_sizes, int n_in,
                              void* d_out, int out_size, void* d_ws, size_t ws_size,
                              hipStream_t stream) {
  (void)in_sizes; (void)n_in; (void)out_size; (void)ws_size;
  const float* Hs    = (const float*)d_in[0];
  const float* Hw    = (const float*)d_in[1];
  const float* HSec  = (const float*)d_in[2];
  const int* w2s     = (const int*)d_in[3];
  const int* s2s     = (const int*)d_in[4];
  const int* S2s     = (const int*)d_in[5];
  const float* Ww_src = (const float*)d_in[6];
  const float* Ww_dst = (const float*)d_in[7];
  const float* aw_src = (const float*)d_in[8];
  const float* aw_dst = (const float*)d_in[9];
  const float* bw     = (const float*)d_in[10];
  const float* Wss    = (const float*)d_in[11];
  const float* as_src = (const float*)d_in[12];
  const float* as_dst = (const float*)d_in[13];
  const float* bs     = (const float*)d_in[14];
  const float* WS_src = (const float*)d_in[15];
  const float* WS_dst = (const float*)d_in[16];
  const float* aS_src = (const float*)d_in[17];
  const float* aS_dst = (const float*)d_in[18];
  const float* bS     = (const float*)d_in[19];
  const float* F1_w   = (const float*)d_in[20];
  const float* F1_b   = (const float*)d_in[21];
  const float* F2_w   = (const float*)d_in[22];
  const float* F2_b   = (const float*)d_in[23];
  const float* l1_w   = (const float*)d_in[24];
  const float* l1_b   = (const float*)d_in[25];
  const float* l2_w   = (const float*)d_in[26];
  const float* l2_b   = (const float*)d_in[27];
  float* outp = (float*)d_out;

  char* ws = (char*)d_ws;
  size_t cur_off = 0;
  auto alloc = [&](size_t bytes) -> char* {
    char* p = ws + cur_off;
    cur_off = (cur_off + bytes + 255) & ~(size_t)255;
    return p;
  };

  __bf16* Wt_w  = (__bf16*)alloc((size_t)5120 * 320 * 2);
  __bf16* Wt_s  = (__bf16*)alloc((size_t)5120 * 640 * 2);
  __bf16* Wt_S  = (__bf16*)alloc((size_t)5120 * 512 * 2);
  __bf16* WtF   = (__bf16*)alloc((size_t)5120 * 10240 * 2);  // F1, then F2
  __bf16* Wt_l2 = (__bf16*)alloc((size_t)640 * 2048 * 2);
  __bf16* l1_bf = (__bf16*)alloc((size_t)5120 * 2048 * 2);
  __bf16* WcT   = (__bf16*)alloc((size_t)640 * 5120 * 2);
  float*  bc    = (float*)alloc(640 * 4);
  __bf16* HS_bf = (__bf16*)alloc((size_t)1024 * 512 * 2);
  __bf16* Hs_bf = (__bf16*)alloc((size_t)kNS * 640 * 2);
  float* v_w = (float*)alloc(8 * 320 * 4);
  float* u_w = (float*)alloc(8 * 640 * 4);
  float* v_s = (float*)alloc(8 * 640 * 4);
  float* u_s = (float*)alloc(8 * 640 * 4);
  float* v_S = (float*)alloc(8 * 512 * 4);
  float* u_S = (float*)alloc(8 * 640 * 4);
  float* alw_s = (float*)alloc((size_t)kNW * 8 * 4);
  float* alw_d = (float*)alloc((size_t)kNS * 8 * 4);
  float* als_s = (float*)alloc((size_t)kNS * 8 * 4);
  float* als_d = (float*)alloc((size_t)kNS * 8 * 4);
  float* alS_s = (float*)alloc((size_t)kNSEC * 8 * 4);
  float* alS_d = (float*)alloc((size_t)kNS * 8 * 4);
  int* csr_i  = (int*)alloc((size_t)6 * kNS * 4);
  int* cnt_w = csr_i, *cnt_s = csr_i + kNS, *cnt_S = csr_i + 2 * kNS;
  int* cur_w = csr_i + 3 * kNS, *cur_s = csr_i + 4 * kNS, *cur_S = csr_i + 5 * kNS;
  int* off_w = (int*)alloc((size_t)(kNS + 1) * 4);
  int* off_s = (int*)alloc((size_t)(kNS + 1) * 4);
  int* off_S = (int*)alloc((size_t)(kNS + 1) * 4);
  int* ssrc_w = (int*)alloc((size_t)kEW * 4);
  int* ssrc_s = (int*)alloc((size_t)kES * 4);
  int* ssrc_S = (int*)alloc((size_t)kESEC * 4);
  __bf16* hs_Sb = (__bf16*)alloc((size_t)1024 * 5120 * 2);
  char* aggreg = alloc((size_t)kNS * 2560 * 2 + (size_t)kNS * 5120 * 2);
  __bf16* agg_w = (__bf16*)aggreg;
  __bf16* agg_s = (__bf16*)(aggreg + (size_t)kNS * 2560 * 2);
  __bf16* U1 = (__bf16*)aggreg;  // alias (agg dead by fusion1)
  __bf16* Uw = (__bf16*)alloc((size_t)kNS * 5120 * 2);
  __bf16* Us = (__bf16*)alloc((size_t)kNS * 5120 * 2);
  __bf16* US = (__bf16*)alloc((size_t)kNS * 5120 * 2);
  __bf16* U2 = Uw;  // alias (Uw dead after fusion1)

  const dim3 b256(256);

  // 1) weight conversions/transposes
  conv_transpose<<<dim3(160, 5), b256, 0, stream>>>(Ww_src, 300, 5120, Wt_w, 320);
  conv_transpose<<<dim3(160, 10), b256, 0, stream>>>(Wss, 640, 5120, Wt_s, 640);
  conv_transpose<<<dim3(160, 8), b256, 0, stream>>>(WS_src, 512, 5120, Wt_S, 512);
  conv_transpose<<<dim3(160, 160), b256, 0, stream>>>(F1_w, 10240, 5120, WtF, 10240);
  conv_transpose<<<dim3(20, 32), b256, 0, stream>>>(l2_w, 2048, 640, Wt_l2, 2048);
  conv_bf<<<(1024 * 512 + 255) / 256, b256, 0, stream>>>(HSec, HS_bf, (long)1024 * 512);
  conv_bf<<<((long)kNS * 640 + 255) / 256, b256, 0, stream>>>(Hs, Hs_bf, (long)kNS * 640);
  conv_bf<<<((long)5120 * 2048 + 255) / 256, b256, 0, stream>>>(l1_w, l1_bf, (long)5120 * 2048);

  // 2) FFN collapse
  gemm_bt<5><<<dim3(40, 5, 1), b256, 0, stream>>>(
      Wt_l2, 2048, nullptr, 1 << 30, l1_bf, 2048, 2048,
      WcT, 5120, nullptr, nullptr, nullptr, 0, nullptr, 0, 0, 0, 0, 0);
  comb_bias<<<3, b256, 0, stream>>>(l1_b, l2_w, l2_b, bc);

  // 3) per-head attention vectors (6 jobs, one launch)
  {
    HVJobs jb;
    jb.j[0] = {Ww_src, aw_src, v_w, 300, 320};
    jb.j[1] = {Ww_dst, aw_dst, u_w, 640, 640};
    jb.j[2] = {Wss,    as_src, v_s, 640, 640};
    jb.j[3] = {Wss,    as_dst, u_s, 640, 640};
    jb.j[4] = {WS_src, aS_src, v_S, 512, 512};
    jb.j[5] = {WS_dst, aS_dst, u_S, 640, 640};
    head_vecs6<<<dim3(8, 160, 6), b256, 0, stream>>>(jb);
  }

  // 4) attention logits
  att_logits<<<(kNW + 3) / 4, b256, 0, stream>>>(Hw, 300, 300, v_w, 320, alw_s, kNW);
  att_logits<<<(kNSEC + 3) / 4, b256, 0, stream>>>(HSec, 512, 512, v_S, 512, alS_s, kNSEC);
  att_logits4<<<(kNS + 3) / 4, b256, 0, stream>>>(Hs, u_w, v_s, u_s, u_S,
                                                  alw_d, als_s, als_d, alS_d, kNS);

  // 5) CSR build (merged launches)
  hipMemsetAsync(csr_i, 0, (size_t)6 * kNS * 4, stream);
  edge_count3<<<(kEW + kES + kESEC + 255) / 256, b256, 0, stream>>>(
      w2s + kEW, kEW, cnt_w, s2s + kES, kES, cnt_s, S2s + kESEC, kESEC, cnt_S);
  scan_off3<<<3, 1024, 0, stream>>>(cnt_w, off_w, cnt_s, off_s, cnt_S, off_S);
  edge_fill3<<<(kEW + kES + kESEC + 255) / 256, b256, 0, stream>>>(
      w2s, w2s + kEW, kEW, off_w, cur_w, ssrc_w,
      s2s, s2s + kES, kES, off_s, cur_s, ssrc_s,
      S2s, S2s + kESEC, kESEC, off_S, cur_S, ssrc_S);

  // 6) section source transform: hs_Sb = HS @ WS_src  (bf16 out)
  gemm_bt<5><<<dim3(40, 8, 1), b256, 0, stream>>>(
      HS_bf, 512, nullptr, 1 << 30, Wt_S, 512, 512,
      hs_Sb, 5120, nullptr, nullptr, nullptr, 0, nullptr, 0, 0, 0, 0, 0);

  // 7) aggregations (w: f32/float4; s,S: bf16/bf16x8)
  gat_agg<320, 300, false, false><<<kNS, b256, 0, stream>>>(off_w, ssrc_w, alw_s, alw_d, Hw, 300, agg_w, 2560, nullptr);
  gat_agg_bf<640, 640, false, false><<<kNS, b256, 0, stream>>>(off_s, ssrc_s, als_s, als_d, Hs_bf, 640, agg_s, 5120, nullptr);
  gat_agg_bf<640, 640, true, true><<<kNS, b256, 0, stream>>>(off_S, ssrc_S, alS_s, alS_d, hs_Sb, 5120, US, 5120, bS);

  // 8) per-head GAT output GEMMs (+bias +ELU)
  gemm_bt<1><<<dim3(5, 64, 8), b256, 0, stream>>>(
      agg_w, 2560, nullptr, 1 << 30, Wt_w, 320, 320,
      Uw, 5120, bw, nullptr, nullptr, 0, nullptr, 0, 320, (long)640 * 320, 640, 640);
  gemm_bt<1><<<dim3(5, 64, 8), b256, 0, stream>>>(
      agg_s, 5120, nullptr, 1 << 30, Wt_s, 640, 640,
      Us, 5120, bs, nullptr, nullptr, 0, nullptr, 0, 640, (long)640 * 640, 640, 640);

  // 9) fusion 1: U1 = z*Uw + (1-z)*Us
  gemm256<2><<<dim3(640), dim3(512), 0, stream>>>(
      Uw, 5120, Us, 5120, WtF, 10240, 10240,
      U1, 5120, F1_b, Uw, Us, 5120, 20);

  // 10) F2 into the freed WtF buffer, then fusion 2 -> U2
  conv_transpose<<<dim3(160, 160), b256, 0, stream>>>(F2_w, 10240, 5120, WtF, 10240);
  gemm256<2><<<dim3(640), dim3(512), 0, stream>>>(
      U1, 5120, US, 5120, WtF, 10240, 10240,
      U2, 5120, F2_b, U1, US, 5120, 20);

  // 11) collapsed FFN: out = U2 @ Wc + bc + Hs
  gemm_bt<4><<<dim3(5, 64, 1), b256, 0, stream>>>(
      U2, 5120, nullptr, 1 << 30, WcT, 5120, 5120,
      outp, 640, bc, nullptr, nullptr, 0, Hs, 640, 0, 0, 0, 0);
}

// Round 10
// 2982.254 us; speedup vs baseline: 1.0362x; 1.0355x over previous
//
#include <hip/hip_runtime.h>
#include <cstdint>
#include <cstddef>

typedef __attribute__((ext_vector_type(8))) __bf16 bf16x8;
typedef __attribute__((ext_vector_type(4))) float f32x4;

static constexpr int kNS   = 8192;
static constexpr int kNW   = 65536;
static constexpr int kNSEC = 1024;
static constexpr int kEW   = 131072;
static constexpr int kES   = 262144;
static constexpr int kESEC = 16384;

__device__ __forceinline__ float eluf(float x)  { return x > 0.f ? x : (__expf(x) - 1.f); }
__device__ __forceinline__ float sigmf(float x) { return 1.f / (1.f + __expf(-x)); }

// async global -> LDS, 16 bytes per lane (dest must be linear in lane order)
__device__ __forceinline__ void gload16(const __bf16* g, __bf16* l) {
  __builtin_amdgcn_global_load_lds((const __attribute__((address_space(1))) unsigned int*)g,
                                   (__attribute__((address_space(3))) unsigned int*)l,
                                   16, 0, 0);
}

// ---------------------------------------------------------------------------
// Weight convert + transpose: W[K][N] f32 -> Wt[N][KP] bf16 (zero-pad k>=K)
// ---------------------------------------------------------------------------
__global__ __launch_bounds__(256) void conv_transpose(const float* __restrict__ W, int K, int N,
                                                      __bf16* __restrict__ Wt, int KP) {
  __shared__ float t[64][33];
  const int nb = blockIdx.x * 32, kb = blockIdx.y * 64;
  const int tx = threadIdx.x & 31, ty = threadIdx.x >> 5;
#pragma unroll
  for (int i = ty; i < 64; i += 8) {
    const int k = kb + i;
    t[i][tx] = (k < K) ? W[(long)k * N + nb + tx] : 0.f;
  }
  __syncthreads();
  union BU { __bf16 b; unsigned short u; };
#pragma unroll
  for (int i = ty; i < 32; i += 8) {
    BU b0, b1;
    b0.b = (__bf16)t[tx * 2][i];
    b1.b = (__bf16)t[tx * 2 + 1][i];
    const unsigned int pk = ((unsigned int)b1.u << 16) | b0.u;
    *(unsigned int*)(Wt + (long)(nb + i) * KP + kb + tx * 2) = pk;
  }
}

__global__ __launch_bounds__(256) void conv_bf(const float* __restrict__ in, __bf16* __restrict__ outb, long n) {
  long i = (long)blockIdx.x * blockDim.x + threadIdx.x;
  if (i < n) outb[i] = (__bf16)in[i];
}

// ---------------------------------------------------------------------------
// Head vectors, 6 jobs in one launch
// ---------------------------------------------------------------------------
struct HVJ { const float* W; const float* a; float* o; int Kd; int KP; };
struct HVJobs { HVJ j[6]; };

__global__ __launch_bounds__(256) void head_vecs6(HVJobs jb) {
  const HVJ J = jb.j[blockIdx.z];
  const int h = blockIdx.x;
  const int lane = threadIdx.x & 63;
  const int k = blockIdx.y * 4 + (threadIdx.x >> 6);
  if (k >= J.KP) return;
  float s = 0.f;
  if (k < J.Kd) {
    const float* wr = J.W + (long)k * 5120 + h * 640;
    const float* ar = J.a + h * 640;
    for (int c = lane; c < 640; c += 64) s += wr[c] * ar[c];
  }
  for (int o2 = 32; o2; o2 >>= 1) s += __shfl_down(s, o2);
  if (lane == 0) J.o[h * J.KP + k] = (k < J.Kd) ? s : 0.f;
}

// Combined FFN bias: bc[n] = sum_k l1_b[k]*l2_w[k][n] + l2_b[n]
__global__ __launch_bounds__(256) void comb_bias(const float* __restrict__ l1_b, const float* __restrict__ l2_w,
                                                 const float* __restrict__ l2_b, float* __restrict__ bc) {
  const int n = blockIdx.x * 256 + threadIdx.x;
  if (n >= 640) return;
  float s = l2_b[n];
  for (int k = 0; k < 2048; ++k) s += l1_b[k] * l2_w[(long)k * 640 + n];
  bc[n] = s;
}

// ---------------------------------------------------------------------------
// Attention logits
// ---------------------------------------------------------------------------
__global__ __launch_bounds__(256) void att_logits(const float* __restrict__ X, int ldx, int Kd,
                                                  const float* __restrict__ vec, int KP,
                                                  float* __restrict__ outl, int N) {
  const int lane = threadIdx.x & 63;
  const int node = blockIdx.x * 4 + (threadIdx.x >> 6);
  if (node >= N) return;
  const float* xr = X + (long)node * ldx;
  float p[8];
#pragma unroll
  for (int h = 0; h < 8; ++h) p[h] = 0.f;
  for (int k = lane; k < Kd; k += 64) {
    const float xv = xr[k];
#pragma unroll
    for (int h = 0; h < 8; ++h) p[h] += xv * vec[h * KP + k];
  }
#pragma unroll
  for (int h = 0; h < 8; ++h) {
    float v = p[h];
    for (int o2 = 32; o2; o2 >>= 1) v += __shfl_down(v, o2);
    if (lane == 0) outl[(long)node * 8 + h] = v;
  }
}

__global__ __launch_bounds__(256) void att_logits4(const float* __restrict__ X,
                                                   const float* __restrict__ v0, const float* __restrict__ v1,
                                                   const float* __restrict__ v2, const float* __restrict__ v3,
                                                   float* __restrict__ o0, float* __restrict__ o1,
                                                   float* __restrict__ o2, float* __restrict__ o3, int N) {
  const int lane = threadIdx.x & 63;
  const int node = blockIdx.x * 4 + (threadIdx.x >> 6);
  if (node >= N) return;
  const float* xr = X + (long)node * 640;
  float p[4][8];
#pragma unroll
  for (int s = 0; s < 4; ++s)
#pragma unroll
    for (int h = 0; h < 8; ++h) p[s][h] = 0.f;
  for (int k = lane; k < 640; k += 64) {
    const float xv = xr[k];
#pragma unroll
    for (int h = 0; h < 8; ++h) {
      p[0][h] += xv * v0[h * 640 + k];
      p[1][h] += xv * v1[h * 640 + k];
      p[2][h] += xv * v2[h * 640 + k];
      p[3][h] += xv * v3[h * 640 + k];
    }
  }
  float* outs[4] = {o0, o1, o2, o3};
#pragma unroll
  for (int s = 0; s < 4; ++s)
#pragma unroll
    for (int h = 0; h < 8; ++h) {
      float v = p[s][h];
      for (int o2v = 32; o2v; o2v >>= 1) v += __shfl_down(v, o2v);
      if (lane == 0) outs[s][(long)node * 8 + h] = v;
    }
}

// ---------------------------------------------------------------------------
// CSR build (3 edge lists per launch)
// ---------------------------------------------------------------------------
__global__ __launch_bounds__(256) void edge_count3(const int* __restrict__ d0, int E0, int* __restrict__ c0,
                                                   const int* __restrict__ d1, int E1, int* __restrict__ c1,
                                                   const int* __restrict__ d2, int E2, int* __restrict__ c2) {
  const int gid = blockIdx.x * blockDim.x + threadIdx.x;
  if (gid < E0) atomicAdd(&c0[d0[gid]], 1);
  else if (gid < E0 + E1) atomicAdd(&c1[d1[gid - E0]], 1);
  else if (gid < E0 + E1 + E2) atomicAdd(&c2[d2[gid - E0 - E1]], 1);
}

__global__ __launch_bounds__(1024) void scan_off3(const int* __restrict__ c0, int* __restrict__ o0,
                                                  const int* __restrict__ c1, int* __restrict__ o1,
                                                  const int* __restrict__ c2, int* __restrict__ o2) {
  const int* cnt = blockIdx.x == 0 ? c0 : (blockIdx.x == 1 ? c1 : c2);
  int* offo = blockIdx.x == 0 ? o0 : (blockIdx.x == 1 ? o1 : o2);
  __shared__ int part[1024];
  const int tid = threadIdx.x;
  const int base = tid * 8;
  int loc[8];
  int s = 0;
#pragma unroll
  for (int i = 0; i < 8; ++i) { loc[i] = s; s += cnt[base + i]; }
  part[tid] = s;
  __syncthreads();
  for (int d2 = 1; d2 < 1024; d2 <<= 1) {
    int v = (tid >= d2) ? part[tid - d2] : 0;
    __syncthreads();
    part[tid] += v;
    __syncthreads();
  }
  const int pre = (tid > 0) ? part[tid - 1] : 0;
#pragma unroll
  for (int i = 0; i < 8; ++i) offo[base + i] = pre + loc[i];
  if (tid == 1023) offo[8192] = part[1023];
}

__global__ __launch_bounds__(256) void edge_fill3(
    const int* __restrict__ s0, const int* __restrict__ d0, int E0, const int* __restrict__ of0, int* __restrict__ cu0, int* __restrict__ sr0,
    const int* __restrict__ s1, const int* __restrict__ d1, int E1, const int* __restrict__ of1, int* __restrict__ cu1, int* __restrict__ sr1,
    const int* __restrict__ s2, const int* __restrict__ d2, int E2, const int* __restrict__ of2, int* __restrict__ cu2, int* __restrict__ sr2) {
  const int gid = blockIdx.x * blockDim.x + threadIdx.x;
  if (gid < E0) {
    const int d = d0[gid];
    sr0[of0[d] + atomicAdd(&cu0[d], 1)] = s0[gid];
  } else if (gid < E0 + E1) {
    const int g = gid - E0, d = d1[g];
    sr1[of1[d] + atomicAdd(&cu1[d], 1)] = s1[g];
  } else if (gid < E0 + E1 + E2) {
    const int g = gid - E0 - E1, d = d2[g];
    sr2[of2[d] + atomicAdd(&cu2[d], 1)] = s2[g];
  }
}

// ---------------------------------------------------------------------------
// GAT aggregation, f32 X (float4) -- word layer (F=300)
// ---------------------------------------------------------------------------
template <int FPAD, int F, bool XPH, bool BIASELU>
__global__ __launch_bounds__(256) void gat_agg(const int* __restrict__ seg_off, const int* __restrict__ ssrc,
                                               const float* __restrict__ als, const float* __restrict__ ald,
                                               const float* __restrict__ X, int ldx,
                                               __bf16* __restrict__ outp, int ldo,
                                               const float* __restrict__ bias) {
  constexpr int C4 = F / 4;
  constexpr int ITEMS = 8 * C4;
  constexpr int L = (ITEMS + 255) / 256;
  const int d = blockIdx.x;
  const int tid = threadIdx.x;
  const int o0 = seg_off[d], o1 = seg_off[d + 1];
  const int deg = o1 - o0;
  __shared__ float exl[64][8];
  __shared__ int ssl[64];
  __shared__ float aldd[8];
  __shared__ float den_s[8];
  if (tid < 8) { aldd[tid] = ald[(long)d * 8 + tid]; den_s[tid] = 0.f; }
  f32x4 acc[L];
  int hh[L], xo[L], oo[L];
  bool vld[L];
#pragma unroll
  for (int l = 0; l < L; ++l) {
    const int idx = tid + l * 256;
    vld[l] = (idx < ITEMS);
    const int h = vld[l] ? (idx / C4) : 0;
    const int c = vld[l] ? (idx - h * C4) : 0;
    hh[l] = h;
    xo[l] = (XPH ? h * F : 0) + c * 4;
    oo[l] = h * FPAD + c * 4;
#pragma unroll
    for (int r = 0; r < 4; ++r) acc[l][r] = 0.f;
  }
  __syncthreads();
  for (int base = 0; base < deg; base += 64) {
    const int nc = min(64, deg - base);
    if (tid < nc) ssl[tid] = ssrc[o0 + base + tid];
    __syncthreads();
    for (int t = tid; t < nc * 8; t += 256) {
      const int e = t >> 3, h = t & 7;
      float v = als[(long)ssl[e] * 8 + h] + aldd[h];
      v = v > 0.f ? v : 0.2f * v;
      exl[e][h] = __expf(v);
    }
    __syncthreads();
    if (tid < 8) {
      float s = 0.f;
      for (int e = 0; e < nc; ++e) s += exl[e][tid];
      den_s[tid] += s;
    }
    for (int e = 0; e < nc; ++e) {
      const float* xr = X + (long)ssl[e] * ldx;
      const float* ex8 = exl[e];
#pragma unroll
      for (int l = 0; l < L; ++l)
        if (vld[l]) {
          const f32x4 v = *(const f32x4*)(xr + xo[l]);
          acc[l] += ex8[hh[l]] * v;
        }
    }
    __syncthreads();
  }
#pragma unroll
  for (int l = 0; l < L; ++l) {
    if (!vld[l]) continue;
    const float dinv = 1.f / (den_s[hh[l]] + 1e-16f);
#pragma unroll
    for (int j = 0; j < 4; ++j) {
      float r = acc[l][j] * dinv;
      if constexpr (BIASELU) { r += bias[oo[l] + j]; r = eluf(r); }
      outp[(long)d * ldo + oo[l] + j] = (__bf16)r;
    }
  }
}

// ---------------------------------------------------------------------------
// GAT aggregation, bf16 X (bf16x8) -- sentence & section layers
// ---------------------------------------------------------------------------
template <int FPAD, int F, bool XPH, bool BIASELU>
__global__ __launch_bounds__(256) void gat_agg_bf(const int* __restrict__ seg_off, const int* __restrict__ ssrc,
                                                  const float* __restrict__ als, const float* __restrict__ ald,
                                                  const __bf16* __restrict__ X, int ldx,
                                                  __bf16* __restrict__ outp, int ldo,
                                                  const float* __restrict__ bias) {
  constexpr int C8 = F / 8;
  constexpr int ITEMS = 8 * C8;
  constexpr int L = (ITEMS + 255) / 256;
  const int d = blockIdx.x;
  const int tid = threadIdx.x;
  const int o0 = seg_off[d], o1 = seg_off[d + 1];
  const int deg = o1 - o0;
  __shared__ float exl[64][8];
  __shared__ int ssl[64];
  __shared__ float aldd[8];
  __shared__ float den_s[8];
  if (tid < 8) { aldd[tid] = ald[(long)d * 8 + tid]; den_s[tid] = 0.f; }
  float acc[L][8];
  int hh[L], xo[L], oo[L];
  bool vld[L];
#pragma unroll
  for (int l = 0; l < L; ++l) {
    const int idx = tid + l * 256;
    vld[l] = (idx < ITEMS);
    const int h = vld[l] ? (idx / C8) : 0;
    const int c = vld[l] ? (idx - h * C8) : 0;
    hh[l] = h;
    xo[l] = (XPH ? h * F : 0) + c * 8;
    oo[l] = h * FPAD + c * 8;
#pragma unroll
    for (int r = 0; r < 8; ++r) acc[l][r] = 0.f;
  }
  __syncthreads();
  for (int base = 0; base < deg; base += 64) {
    const int nc = min(64, deg - base);
    if (tid < nc) ssl[tid] = ssrc[o0 + base + tid];
    __syncthreads();
    for (int t = tid; t < nc * 8; t += 256) {
      const int e = t >> 3, h = t & 7;
      float v = als[(long)ssl[e] * 8 + h] + aldd[h];
      v = v > 0.f ? v : 0.2f * v;
      exl[e][h] = __expf(v);
    }
    __syncthreads();
    if (tid < 8) {
      float s = 0.f;
      for (int e = 0; e < nc; ++e) s += exl[e][tid];
      den_s[tid] += s;
    }
    for (int e = 0; e < nc; ++e) {
      const __bf16* xr = X + (long)ssl[e] * ldx;
      const float* ex8 = exl[e];
#pragma unroll
      for (int l = 0; l < L; ++l)
        if (vld[l]) {
          const bf16x8 v = *(const bf16x8*)(xr + xo[l]);
          const float w = ex8[hh[l]];
#pragma unroll
          for (int r = 0; r < 8; ++r) acc[l][r] += w * (float)v[r];
        }
    }
    __syncthreads();
  }
#pragma unroll
  for (int l = 0; l < L; ++l) {
    if (!vld[l]) continue;
    const float dinv = 1.f / (den_s[hh[l]] + 1e-16f);
#pragma unroll
    for (int j = 0; j < 8; ++j) {
      float r = acc[l][j] * dinv;
      if constexpr (BIASELU) { r += bias[oo[l] + j]; r = eluf(r); }
      outp[(long)d * ldo + oo[l] + j] = (__bf16)r;
    }
  }
}

// ---------------------------------------------------------------------------
// 128x128-tile MFMA GEMM (m97-class, 2-barrier) -- small/batched GEMMs.
// EPI: 0 store f32 | 1 bias+ELU->bf16 | 2 sigmoid-gate mix->bf16
//      3 bias->bf16 | 4 bias+residual->f32 | 5 store bf16
// ---------------------------------------------------------------------------
template <int EPI>
__global__ __launch_bounds__(256) void gemm_bt(
    const __bf16* __restrict__ A, int lda, const __bf16* __restrict__ A2, int ksplit,
    const __bf16* __restrict__ Bt, int ldb, int K,
    void* __restrict__ Cout, int ldc,
    const float* __restrict__ bias,
    const __bf16* __restrict__ Xg, const __bf16* __restrict__ Yg, int ldxy,
    const float* __restrict__ Res, int ldres,
    long a_zs, long bt_zs, long c_zs, int b_zs) {
  __shared__ __bf16 sA[2][128 * 32];
  __shared__ __bf16 sB[2][128 * 32];
  const int tid = threadIdx.x;
  const int z = blockIdx.z;
  const int m0 = blockIdx.y * 128, n0 = blockIdx.x * 128;
  const __bf16* Ab = A + (long)z * a_zs;
  const __bf16* A2b = A2 ? A2 + (long)z * a_zs : nullptr;
  const __bf16* Btb = Bt + (long)z * bt_zs;
  const int lane = tid & 63;
  const int wv = tid >> 6, wr = wv >> 1, wc = wv & 1;
  const int fr = lane & 15, fq = lane >> 4;

  const int r0 = tid >> 2, r1 = r0 + 64;
  const int csw = (((tid & 3) ^ ((r0 >> 1) & 3)) * 8);
  const int ldst0 = tid * 8;
  const int ldst1 = 2048 + tid * 8;

  f32x4 acc[4][4];
#pragma unroll
  for (int i = 0; i < 4; ++i)
#pragma unroll
    for (int j = 0; j < 4; ++j)
#pragma unroll
      for (int r = 0; r < 4; ++r) acc[i][j][r] = 0.f;

  const int fsw = (fq ^ ((fr >> 1) & 3)) * 8;
  int aof[4], bof[4];
#pragma unroll
  for (int i = 0; i < 4; ++i) {
    aof[i] = (wr * 64 + i * 16 + fr) * 32 + fsw;
    bof[i] = (wc * 64 + i * 16 + fr) * 32 + fsw;
  }

  const int nkt = K >> 5;
  auto stage = [&](int buf, int kt) {
    const int k0 = kt * 32;
    const __bf16* As = Ab;
    int kr = k0;
    if (A2b && k0 >= ksplit) { As = A2b; kr = k0 - ksplit; }
    gload16(As + (long)(m0 + r0) * lda + kr + csw, &sA[buf][ldst0]);
    gload16(As + (long)(m0 + r1) * lda + kr + csw, &sA[buf][ldst1]);
    gload16(Btb + (long)(n0 + r0) * ldb + k0 + csw, &sB[buf][ldst0]);
    gload16(Btb + (long)(n0 + r1) * ldb + k0 + csw, &sB[buf][ldst1]);
  };

  stage(0, 0);
  for (int kt = 0; kt < nkt; ++kt) {
    const int cur = kt & 1;
    __syncthreads();
    if (kt + 1 < nkt) stage(cur ^ 1, kt + 1);
    bf16x8 af[4], bfv[4];
#pragma unroll
    for (int i = 0; i < 4; ++i) {
      af[i] = *(const bf16x8*)(&sA[cur][aof[i]]);
      bfv[i] = *(const bf16x8*)(&sB[cur][bof[i]]);
    }
#pragma unroll
    for (int i = 0; i < 4; ++i)
#pragma unroll
      for (int j = 0; j < 4; ++j)
        acc[i][j] = __builtin_amdgcn_mfma_f32_16x16x32_bf16(af[i], bfv[j], acc[i][j], 0, 0, 0);
  }

  const float* biasb = bias ? bias + (long)z * b_zs : nullptr;
#pragma unroll
  for (int i = 0; i < 4; ++i) {
#pragma unroll
    for (int j = 0; j < 4; ++j) {
#pragma unroll
      for (int r = 0; r < 4; ++r) {
        const int mm = m0 + wr * 64 + i * 16 + fq * 4 + r;
        const int nn = n0 + wc * 64 + j * 16 + fr;
        const float v = acc[i][j][r];
        const long cidx = (long)mm * ldc + nn + (long)z * c_zs;
        if constexpr (EPI == 0) {
          ((float*)Cout)[cidx] = v;
        } else if constexpr (EPI == 1) {
          ((__bf16*)Cout)[cidx] = (__bf16)eluf(v + biasb[nn]);
        } else if constexpr (EPI == 2) {
          const float zt = sigmf(v + biasb[nn]);
          const float x = (float)Xg[(long)mm * ldxy + nn];
          const float y = (float)Yg[(long)mm * ldxy + nn];
          ((__bf16*)Cout)[cidx] = (__bf16)(zt * x + (1.f - zt) * y);
        } else if constexpr (EPI == 3) {
          ((__bf16*)Cout)[cidx] = (__bf16)(v + biasb[nn]);
        } else if constexpr (EPI == 4) {
          ((float*)Cout)[cidx] = v + biasb[nn] + Res[(long)mm * ldres + nn];
        } else {
          ((__bf16*)Cout)[cidx] = (__bf16)v;
        }
      }
    }
  }
}

// ---------------------------------------------------------------------------
// 256x256-tile 8-wave MFMA GEMM, hoisted-reads pipeline (R7 structure,
// 16x16x32 MFMA -- proven 940us / MfmaUtil 45% / 0 bank conflicts).
// 2 barriers/K-tile, each carrying the vmcnt drain:
//   B1: after stageB(nb,k0)+vmcnt(4)  -> validates cb k1 for this tile
//   B3: after stageB(nb,k1)+vmcnt(4)  -> validates nb k0 for next tile
// Every MFMA cluster's ds_reads are issued >=1 cluster earlier with counted
// lgkmcnt + sched_barrier(0) so LDS delivery overlaps the previous cluster.
// EPI: 2 sigmoid-gate mix->bf16 | 3 bias->bf16
// ---------------------------------------------------------------------------
template <int EPI>
__global__ __launch_bounds__(512, 2) void gemm256(
    const __bf16* __restrict__ A, int lda, const __bf16* __restrict__ A2, int ksplit,
    const __bf16* __restrict__ Bt, int ldb, int K,
    void* __restrict__ Cout, int ldc,
    const float* __restrict__ bias,
    const __bf16* __restrict__ Xg, const __bf16* __restrict__ Yg, int ldxy,
    int nn_tiles) {
  __shared__ __bf16 sA[2][2][256 * 32];
  __shared__ __bf16 sB[2][2][256 * 32];
  const int tid = threadIdx.x;

  const int nwg = gridDim.x;
  const int lin = blockIdx.x;
  const int qq = nwg >> 3, rr = nwg & 7;
  const int xcd = lin & 7, pos = lin >> 3;
  const int swz = (xcd < rr ? xcd * (qq + 1) : rr * (qq + 1) + (xcd - rr) * qq) + pos;
  const int m0 = (swz / nn_tiles) * 256;
  const int n0 = (swz % nn_tiles) * 256;

  const int lane = tid & 63;
  const int wv = tid >> 6, wm = wv >> 2, wn = wv & 3;
  const int fr = lane & 15, fq = lane >> 4;

  const int srow = tid >> 2;
  const int pslot = tid & 3;

  auto stageA = [&](int bp, int tt, int kk) {
    const int kcol0 = tt * 64 + kk * 32;
    const __bf16* src = A;
    int kc = kcol0;
    if (A2 && kcol0 >= ksplit) { src = A2; kc = kcol0 - ksplit; }
    __bf16* dst = &sA[bp][kk][0];
#pragma unroll
    for (int i = 0; i < 2; ++i) {
      const int r = i * 128 + srow;
      const int l = pslot ^ ((r >> 1) & 3);
      gload16(src + (long)(m0 + r) * lda + kc + l * 8, dst + (i * 512 + tid) * 8);
    }
  };
  auto stageB = [&](int bp, int tt, int kk) {
    const int kcol0 = tt * 64 + kk * 32;
    __bf16* dst = &sB[bp][kk][0];
#pragma unroll
    for (int i = 0; i < 2; ++i) {
      const int r = i * 128 + srow;
      const int l = pslot ^ ((r >> 1) & 3);
      gload16(Bt + (long)(n0 + r) * ldb + kcol0 + l * 8, dst + (i * 512 + tid) * 8);
    }
  };

  int aoff[8], boff[4];
#pragma unroll
  for (int mf = 0; mf < 8; ++mf) {
    const int ra = wm * 128 + mf * 16 + fr;
    aoff[mf] = ra * 32 + ((fq ^ ((ra >> 1) & 3)) * 8);
  }
#pragma unroll
  for (int nf = 0; nf < 4; ++nf) {
    const int rb = wn * 64 + nf * 16 + fr;
    boff[nf] = rb * 32 + ((fq ^ ((rb >> 1) & 3)) * 8);
  }

  f32x4 acc[8][4];
#pragma unroll
  for (int i = 0; i < 8; ++i)
#pragma unroll
    for (int j = 0; j < 4; ++j)
#pragma unroll
      for (int r = 0; r < 4; ++r) acc[i][j][r] = 0.f;

  const int nkt = K >> 6;

  bf16x8 aA[4], aB[4], bA[4], bB[4];

  // prologue: stage tile 0; k0 halves ready at vmcnt(4); then pre-read q0 frags
  stageA(0, 0, 0); stageB(0, 0, 0); stageA(0, 0, 1); stageB(0, 0, 1);
  asm volatile("s_waitcnt vmcnt(4)" ::: "memory");
  __builtin_amdgcn_s_barrier();
#pragma unroll
  for (int mf = 0; mf < 4; ++mf) aA[mf] = *(const bf16x8*)(&sA[0][0][aoff[mf]]);
#pragma unroll
  for (int nf = 0; nf < 4; ++nf) bA[nf] = *(const bf16x8*)(&sB[0][0][boff[nf]]);

  for (int t = 0; t < nkt; ++t) {
    const int cb = t & 1, nb = cb ^ 1;
    const bool pf = (t + 1 < nkt);

    // q1 reads (cb k0, A 4-7) -- hoisted above q0 MFMA
#pragma unroll
    for (int mf = 0; mf < 4; ++mf) aB[mf] = *(const bf16x8*)(&sA[cb][0][aoff[4 + mf]]);
    if (pf) stageA(nb, t + 1, 0);
    asm volatile("s_waitcnt lgkmcnt(4)" ::: "memory");  // aA,bA done (aB in flight)
    __builtin_amdgcn_sched_barrier(0);
    __builtin_amdgcn_s_setprio(1);
#pragma unroll
    for (int mf = 0; mf < 4; ++mf)
#pragma unroll
      for (int nf = 0; nf < 4; ++nf)
        acc[mf][nf] = __builtin_amdgcn_mfma_f32_16x16x32_bf16(aA[mf], bA[nf], acc[mf][nf], 0, 0, 0);
    __builtin_amdgcn_s_setprio(0);
    __builtin_amdgcn_sched_barrier(0);

    if (pf) stageB(nb, t + 1, 0);
    if (pf) asm volatile("s_waitcnt vmcnt(4)" ::: "memory");  // drains t's k1 (cb k1)
    else    asm volatile("s_waitcnt vmcnt(0)" ::: "memory");
    __builtin_amdgcn_s_barrier();  // B1: cb k1 valid for all waves

    // q2 reads (cb k1, A 0-3 + B 0-3) -- hoisted above q1 MFMA
#pragma unroll
    for (int mf = 0; mf < 4; ++mf) aA[mf] = *(const bf16x8*)(&sA[cb][1][aoff[mf]]);
#pragma unroll
    for (int nf = 0; nf < 4; ++nf) bB[nf] = *(const bf16x8*)(&sB[cb][1][boff[nf]]);
    asm volatile("s_waitcnt lgkmcnt(8)" ::: "memory");  // aB done (aA,bB in flight)
    __builtin_amdgcn_sched_barrier(0);
    __builtin_amdgcn_s_setprio(1);
#pragma unroll
    for (int mf = 0; mf < 4; ++mf)
#pragma unroll
      for (int nf = 0; nf < 4; ++nf)
        acc[4 + mf][nf] = __builtin_amdgcn_mfma_f32_16x16x32_bf16(aB[mf], bA[nf], acc[4 + mf][nf], 0, 0, 0);
    __builtin_amdgcn_s_setprio(0);
    __builtin_amdgcn_sched_barrier(0);

    // q3 reads (cb k1, A 4-7) -- hoisted above q2 MFMA
#pragma unroll
    for (int mf = 0; mf < 4; ++mf) aB[mf] = *(const bf16x8*)(&sA[cb][1][aoff[4 + mf]]);
    if (pf) stageA(nb, t + 1, 1);
    asm volatile("s_waitcnt lgkmcnt(4)" ::: "memory");  // aA,bB done (aB in flight)
    __builtin_amdgcn_sched_barrier(0);
    __builtin_amdgcn_s_setprio(1);
#pragma unroll
    for (int mf = 0; mf < 4; ++mf)
#pragma unroll
      for (int nf = 0; nf < 4; ++nf)
        acc[mf][nf] = __builtin_amdgcn_mfma_f32_16x16x32_bf16(aA[mf], bB[nf], acc[mf][nf], 0, 0, 0);
    __builtin_amdgcn_s_setprio(0);
    __builtin_amdgcn_sched_barrier(0);

    if (pf) {
      stageB(nb, t + 1, 1);
      asm volatile("s_waitcnt vmcnt(4)" ::: "memory");  // drains t+1's k0 (nb k0)
    }
    __builtin_amdgcn_s_barrier();  // B3: nb k0 valid for all waves

    // next-tile q0 reads (nb k0, A 0-3 + B 0-3) -- hoisted above q3 MFMA
    if (pf) {
#pragma unroll
      for (int mf = 0; mf < 4; ++mf) aA[mf] = *(const bf16x8*)(&sA[nb][0][aoff[mf]]);
#pragma unroll
      for (int nf = 0; nf < 4; ++nf) bA[nf] = *(const bf16x8*)(&sB[nb][0][boff[nf]]);
      asm volatile("s_waitcnt lgkmcnt(8)" ::: "memory");  // aB done (aA,bA in flight)
    } else {
      asm volatile("s_waitcnt lgkmcnt(0)" ::: "memory");
    }
    __builtin_amdgcn_sched_barrier(0);
    __builtin_amdgcn_s_setprio(1);
#pragma unroll
    for (int mf = 0; mf < 4; ++mf)
#pragma unroll
      for (int nf = 0; nf < 4; ++nf)
        acc[4 + mf][nf] = __builtin_amdgcn_mfma_f32_16x16x32_bf16(aB[mf], bB[nf], acc[4 + mf][nf], 0, 0, 0);
    __builtin_amdgcn_s_setprio(0);
    __builtin_amdgcn_sched_barrier(0);
  }

  // epilogue
#pragma unroll
  for (int mf = 0; mf < 8; ++mf) {
#pragma unroll
    for (int nf = 0; nf < 4; ++nf) {
#pragma unroll
      for (int r = 0; r < 4; ++r) {
        const int mm = m0 + wm * 128 + mf * 16 + fq * 4 + r;
        const int nn = n0 + wn * 64 + nf * 16 + fr;
        const float v = acc[mf][nf][r];
        const long cidx = (long)mm * ldc + nn;
        if constexpr (EPI == 2) {
          const float zt = sigmf(v + bias[nn]);
          const float x = (float)Xg[(long)mm * ldxy + nn];
          const float y = (float)Yg[(long)mm * ldxy + nn];
          ((__bf16*)Cout)[cidx] = (__bf16)(zt * x + (1.f - zt) * y);
        } else {
          ((__bf16*)Cout)[cidx] = (__bf16)(v + bias[nn]);
        }
      }
    }
  }
}

// ---------------------------------------------------------------------------
extern "C" void kernel_launch(void* const* d_in, const int* in_sizes, int n_in,
                              void* d_out, int out_size, void* d_ws, size_t ws_size,
                              hipStream_t stream) {
  (void)in_sizes; (void)n_in; (void)out_size; (void)ws_size;
  const float* Hs    = (const float*)d_in[0];
  const float* Hw    = (const float*)d_in[1];
  const float* HSec  = (const float*)d_in[2];
  const int* w2s     = (const int*)d_in[3];
  const int* s2s     = (const int*)d_in[4];
  const int* S2s     = (const int*)d_in[5];
  const float* Ww_src = (const float*)d_in[6];
  const float* Ww_dst = (const float*)d_in[7];
  const float* aw_src = (const float*)d_in[8];
  const float* aw_dst = (const float*)d_in[9];
  const float* bw     = (const float*)d_in[10];
  const float* Wss    = (const float*)d_in[11];
  const float* as_src = (const float*)d_in[12];
  const float* as_dst = (const float*)d_in[13];
  const float* bs     = (const float*)d_in[14];
  const float* WS_src = (const float*)d_in[15];
  const float* WS_dst = (const float*)d_in[16];
  const float* aS_src = (const float*)d_in[17];
  const float* aS_dst = (const float*)d_in[18];
  const float* bS     = (const float*)d_in[19];
  const float* F1_w   = (const float*)d_in[20];
  const float* F1_b   = (const float*)d_in[21];
  const float* F2_w   = (const float*)d_in[22];
  const float* F2_b   = (const float*)d_in[23];
  const float* l1_w   = (const float*)d_in[24];
  const float* l1_b   = (const float*)d_in[25];
  const float* l2_w   = (const float*)d_in[26];
  const float* l2_b   = (const float*)d_in[27];
  float* outp = (float*)d_out;

  char* ws = (char*)d_ws;
  size_t cur_off = 0;
  auto alloc = [&](size_t bytes) -> char* {
    char* p = ws + cur_off;
    cur_off = (cur_off + bytes + 255) & ~(size_t)255;
    return p;
  };

  __bf16* Wt_w  = (__bf16*)alloc((size_t)5120 * 320 * 2);
  __bf16* Wt_s  = (__bf16*)alloc((size_t)5120 * 640 * 2);
  __bf16* Wt_S  = (__bf16*)alloc((size_t)5120 * 512 * 2);
  __bf16* WtF   = (__bf16*)alloc((size_t)5120 * 10240 * 2);  // F1, then F2
  __bf16* Wt_l2 = (__bf16*)alloc((size_t)640 * 2048 * 2);
  __bf16* l1_bf = (__bf16*)alloc((size_t)5120 * 2048 * 2);
  __bf16* WcT   = (__bf16*)alloc((size_t)640 * 5120 * 2);
  float*  bc    = (float*)alloc(640 * 4);
  __bf16* HS_bf = (__bf16*)alloc((size_t)1024 * 512 * 2);
  __bf16* Hs_bf = (__bf16*)alloc((size_t)kNS * 640 * 2);
  float* v_w = (float*)alloc(8 * 320 * 4);
  float* u_w = (float*)alloc(8 * 640 * 4);
  float* v_s = (float*)alloc(8 * 640 * 4);
  float* u_s = (float*)alloc(8 * 640 * 4);
  float* v_S = (float*)alloc(8 * 512 * 4);
  float* u_S = (float*)alloc(8 * 640 * 4);
  float* alw_s = (float*)alloc((size_t)kNW * 8 * 4);
  float* alw_d = (float*)alloc((size_t)kNS * 8 * 4);
  float* als_s = (float*)alloc((size_t)kNS * 8 * 4);
  float* als_d = (float*)alloc((size_t)kNS * 8 * 4);
  float* alS_s = (float*)alloc((size_t)kNSEC * 8 * 4);
  float* alS_d = (float*)alloc((size_t)kNS * 8 * 4);
  int* csr_i  = (int*)alloc((size_t)6 * kNS * 4);
  int* cnt_w = csr_i, *cnt_s = csr_i + kNS, *cnt_S = csr_i + 2 * kNS;
  int* cur_w = csr_i + 3 * kNS, *cur_s = csr_i + 4 * kNS, *cur_S = csr_i + 5 * kNS;
  int* off_w = (int*)alloc((size_t)(kNS + 1) * 4);
  int* off_s = (int*)alloc((size_t)(kNS + 1) * 4);
  int* off_S = (int*)alloc((size_t)(kNS + 1) * 4);
  int* ssrc_w = (int*)alloc((size_t)kEW * 4);
  int* ssrc_s = (int*)alloc((size_t)kES * 4);
  int* ssrc_S = (int*)alloc((size_t)kESEC * 4);
  __bf16* hs_Sb = (__bf16*)alloc((size_t)1024 * 5120 * 2);
  char* aggreg = alloc((size_t)kNS * 2560 * 2 + (size_t)kNS * 5120 * 2);
  __bf16* agg_w = (__bf16*)aggreg;
  __bf16* agg_s = (__bf16*)(aggreg + (size_t)kNS * 2560 * 2);
  __bf16* U1 = (__bf16*)aggreg;  // alias (agg dead by fusion1)
  __bf16* Uw = (__bf16*)alloc((size_t)kNS * 5120 * 2);
  __bf16* Us = (__bf16*)alloc((size_t)kNS * 5120 * 2);
  __bf16* US = (__bf16*)alloc((size_t)kNS * 5120 * 2);
  __bf16* U2 = Uw;  // alias (Uw dead after fusion1)

  const dim3 b256(256);

  // 1) weight conversions/transposes
  conv_transpose<<<dim3(160, 5), b256, 0, stream>>>(Ww_src, 300, 5120, Wt_w, 320);
  conv_transpose<<<dim3(160, 10), b256, 0, stream>>>(Wss, 640, 5120, Wt_s, 640);
  conv_transpose<<<dim3(160, 8), b256, 0, stream>>>(WS_src, 512, 5120, Wt_S, 512);
  conv_transpose<<<dim3(160, 160), b256, 0, stream>>>(F1_w, 10240, 5120, WtF, 10240);
  conv_transpose<<<dim3(20, 32), b256, 0, stream>>>(l2_w, 2048, 640, Wt_l2, 2048);
  conv_bf<<<(1024 * 512 + 255) / 256, b256, 0, stream>>>(HSec, HS_bf, (long)1024 * 512);
  conv_bf<<<((long)kNS * 640 + 255) / 256, b256, 0, stream>>>(Hs, Hs_bf, (long)kNS * 640);
  conv_bf<<<((long)5120 * 2048 + 255) / 256, b256, 0, stream>>>(l1_w, l1_bf, (long)5120 * 2048);

  // 2) FFN collapse
  gemm_bt<5><<<dim3(40, 5, 1), b256, 0, stream>>>(
      Wt_l2, 2048, nullptr, 1 << 30, l1_bf, 2048, 2048,
      WcT, 5120, nullptr, nullptr, nullptr, 0, nullptr, 0, 0, 0, 0, 0);
  comb_bias<<<3, b256, 0, stream>>>(l1_b, l2_w, l2_b, bc);

  // 3) per-head attention vectors (6 jobs, one launch)
  {
    HVJobs jb;
    jb.j[0] = {Ww_src, aw_src, v_w, 300, 320};
    jb.j[1] = {Ww_dst, aw_dst, u_w, 640, 640};
    jb.j[2] = {Wss,    as_src, v_s, 640, 640};
    jb.j[3] = {Wss,    as_dst, u_s, 640, 640};
    jb.j[4] = {WS_src, aS_src, v_S, 512, 512};
    jb.j[5] = {WS_dst, aS_dst, u_S, 640, 640};
    head_vecs6<<<dim3(8, 160, 6), b256, 0, stream>>>(jb);
  }

  // 4) attention logits
  att_logits<<<(kNW + 3) / 4, b256, 0, stream>>>(Hw, 300, 300, v_w, 320, alw_s, kNW);
  att_logits<<<(kNSEC + 3) / 4, b256, 0, stream>>>(HSec, 512, 512, v_S, 512, alS_s, kNSEC);
  att_logits4<<<(kNS + 3) / 4, b256, 0, stream>>>(Hs, u_w, v_s, u_s, u_S,
                                                  alw_d, als_s, als_d, alS_d, kNS);

  // 5) CSR build (merged launches)
  hipMemsetAsync(csr_i, 0, (size_t)6 * kNS * 4, stream);
  edge_count3<<<(kEW + kES + kESEC + 255) / 256, b256, 0, stream>>>(
      w2s + kEW, kEW, cnt_w, s2s + kES, kES, cnt_s, S2s + kESEC, kESEC, cnt_S);
  scan_off3<<<3, 1024, 0, stream>>>(cnt_w, off_w, cnt_s, off_s, cnt_S, off_S);
  edge_fill3<<<(kEW + kES + kESEC + 255) / 256, b256, 0, stream>>>(
      w2s, w2s + kEW, kEW, off_w, cur_w, ssrc_w,
      s2s, s2s + kES, kES, off_s, cur_s, ssrc_s,
      S2s, S2s + kESEC, kESEC, off_S, cur_S, ssrc_S);

  // 6) section source transform: hs_Sb = HS @ WS_src  (bf16 out)
  gemm_bt<5><<<dim3(40, 8, 1), b256, 0, stream>>>(
      HS_bf, 512, nullptr, 1 << 30, Wt_S, 512, 512,
      hs_Sb, 5120, nullptr, nullptr, nullptr, 0, nullptr, 0, 0, 0, 0, 0);

  // 7) aggregations (w: f32/float4; s,S: bf16/bf16x8)
  gat_agg<320, 300, false, false><<<kNS, b256, 0, stream>>>(off_w, ssrc_w, alw_s, alw_d, Hw, 300, agg_w, 2560, nullptr);
  gat_agg_bf<640, 640, false, false><<<kNS, b256, 0, stream>>>(off_s, ssrc_s, als_s, als_d, Hs_bf, 640, agg_s, 5120, nullptr);
  gat_agg_bf<640, 640, true, true><<<kNS, b256, 0, stream>>>(off_S, ssrc_S, alS_s, alS_d, hs_Sb, 5120, US, 5120, bS);

  // 8) per-head GAT output GEMMs (+bias +ELU)
  gemm_bt<1><<<dim3(5, 64, 8), b256, 0, stream>>>(
      agg_w, 2560, nullptr, 1 << 30, Wt_w, 320, 320,
      Uw, 5120, bw, nullptr, nullptr, 0, nullptr, 0, 320, (long)640 * 320, 640, 640);
  gemm_bt<1><<<dim3(5, 64, 8), b256, 0, stream>>>(
      agg_s, 5120, nullptr, 1 << 30, Wt_s, 640, 640,
      Us, 5120, bs, nullptr, nullptr, 0, nullptr, 0, 640, (long)640 * 640, 640, 640);

  // 9) fusion 1: U1 = z*Uw + (1-z)*Us
  gemm256<2><<<dim3(640), dim3(512), 0, stream>>>(
      Uw, 5120, Us, 5120, WtF, 10240, 10240,
      U1, 5120, F1_b, Uw, Us, 5120, 20);

  // 10) F2 into the freed WtF buffer, then fusion 2 -> U2
  conv_transpose<<<dim3(160, 160), b256, 0, stream>>>(F2_w, 10240, 5120, WtF, 10240);
  gemm256<2><<<dim3(640), dim3(512), 0, stream>>>(
      U1, 5120, US, 5120, WtF, 10240, 10240,
      U2, 5120, F2_b, U1, US, 5120, 20);

  // 11) collapsed FFN: out = U2 @ Wc + bc + Hs
  gemm_bt<4><<<dim3(5, 64, 1), b256, 0, stream>>>(
      U2, 5120, nullptr, 1 << 30, WcT, 5120, 5120,
      outp, 640, bc, nullptr, nullptr, 0, Hs, 640, 0, 0, 0, 0);
}

// Round 11
// 2872.388 us; speedup vs baseline: 1.0758x; 1.0382x over previous
//
#include <hip/hip_runtime.h>
#include <cstdint>
#include <cstddef>

typedef __attribute__((ext_vector_type(8))) __bf16 bf16x8;
typedef __attribute__((ext_vector_type(4))) float f32x4;

static constexpr int kNS   = 8192;
static constexpr int kNW   = 65536;
static constexpr int kNSEC = 1024;
static constexpr int kEW   = 131072;
static constexpr int kES   = 262144;
static constexpr int kESEC = 16384;

__device__ __forceinline__ float eluf(float x)  { return x > 0.f ? x : (__expf(x) - 1.f); }
__device__ __forceinline__ float sigmf(float x) { return 1.f / (1.f + __expf(-x)); }

// async global -> LDS, 16 bytes per lane (dest must be linear in lane order)
__device__ __forceinline__ void gload16(const __bf16* g, __bf16* l) {
  __builtin_amdgcn_global_load_lds((const __attribute__((address_space(1))) unsigned int*)g,
                                   (__attribute__((address_space(3))) unsigned int*)l,
                                   16, 0, 0);
}

// ---------------------------------------------------------------------------
// Weight convert + transpose: W[K][N] f32 -> Wt[N][KP] bf16 (zero-pad k>=K)
// ---------------------------------------------------------------------------
__global__ __launch_bounds__(256) void conv_transpose(const float* __restrict__ W, int K, int N,
                                                      __bf16* __restrict__ Wt, int KP) {
  __shared__ float t[64][33];
  const int nb = blockIdx.x * 32, kb = blockIdx.y * 64;
  const int tx = threadIdx.x & 31, ty = threadIdx.x >> 5;
#pragma unroll
  for (int i = ty; i < 64; i += 8) {
    const int k = kb + i;
    t[i][tx] = (k < K) ? W[(long)k * N + nb + tx] : 0.f;
  }
  __syncthreads();
  union BU { __bf16 b; unsigned short u; };
#pragma unroll
  for (int i = ty; i < 32; i += 8) {
    BU b0, b1;
    b0.b = (__bf16)t[tx * 2][i];
    b1.b = (__bf16)t[tx * 2 + 1][i];
    const unsigned int pk = ((unsigned int)b1.u << 16) | b0.u;
    *(unsigned int*)(Wt + (long)(nb + i) * KP + kb + tx * 2) = pk;
  }
}

// vectorized f32 -> bf16 convert: 4 elements per thread (16B read, 8B write)
__global__ __launch_bounds__(256) void conv_bf4(const float* __restrict__ in, __bf16* __restrict__ outb, long n4) {
  const long i = (long)blockIdx.x * blockDim.x + threadIdx.x;
  if (i >= n4) return;
  const f32x4 v = *(const f32x4*)(in + i * 4);
  union { __bf16 b[4]; uint2 u; } p;
  p.b[0] = (__bf16)v[0]; p.b[1] = (__bf16)v[1];
  p.b[2] = (__bf16)v[2]; p.b[3] = (__bf16)v[3];
  *(uint2*)(outb + i * 4) = p.u;
}

// ---------------------------------------------------------------------------
// Head vectors, 6 jobs in one launch
// ---------------------------------------------------------------------------
struct HVJ { const float* W; const float* a; float* o; int Kd; int KP; };
struct HVJobs { HVJ j[6]; };

__global__ __launch_bounds__(256) void head_vecs6(HVJobs jb) {
  const HVJ J = jb.j[blockIdx.z];
  const int h = blockIdx.x;
  const int lane = threadIdx.x & 63;
  const int k = blockIdx.y * 4 + (threadIdx.x >> 6);
  if (k >= J.KP) return;
  float s = 0.f;
  if (k < J.Kd) {
    const float* wr = J.W + (long)k * 5120 + h * 640;
    const float* ar = J.a + h * 640;
    for (int c = lane; c < 640; c += 64) s += wr[c] * ar[c];
  }
  for (int o2 = 32; o2; o2 >>= 1) s += __shfl_down(s, o2);
  if (lane == 0) J.o[h * J.KP + k] = (k < J.Kd) ? s : 0.f;
}

// Combined FFN bias: bc[n] = sum_k l1_b[k]*l2_w[k][n] + l2_b[n]
// 20 blocks x 256 threads: thread = (k-lane ko 0..7, n-col no 0..31); coalesced.
__global__ __launch_bounds__(256) void comb_bias(const float* __restrict__ l1_b, const float* __restrict__ l2_w,
                                                 const float* __restrict__ l2_b, float* __restrict__ bc) {
  __shared__ float red[8][32];
  const int no = threadIdx.x & 31;
  const int ko = threadIdx.x >> 5;
  const int n = blockIdx.x * 32 + no;
  float s = 0.f;
  for (int k = ko; k < 2048; k += 8) s += l1_b[k] * l2_w[(long)k * 640 + n];
  red[ko][no] = s;
  __syncthreads();
  if (threadIdx.x < 32) {
    const int nn = blockIdx.x * 32 + threadIdx.x;
    float t = l2_b[nn];
#pragma unroll
    for (int i = 0; i < 8; ++i) t += red[i][threadIdx.x];
    bc[nn] = t;
  }
}

// ---------------------------------------------------------------------------
// Attention logits
// ---------------------------------------------------------------------------
__global__ __launch_bounds__(256) void att_logits(const float* __restrict__ X, int ldx, int Kd,
                                                  const float* __restrict__ vec, int KP,
                                                  float* __restrict__ outl, int N) {
  const int lane = threadIdx.x & 63;
  const int node = blockIdx.x * 4 + (threadIdx.x >> 6);
  if (node >= N) return;
  const float* xr = X + (long)node * ldx;
  float p[8];
#pragma unroll
  for (int h = 0; h < 8; ++h) p[h] = 0.f;
  for (int k = lane; k < Kd; k += 64) {
    const float xv = xr[k];
#pragma unroll
    for (int h = 0; h < 8; ++h) p[h] += xv * vec[h * KP + k];
  }
#pragma unroll
  for (int h = 0; h < 8; ++h) {
    float v = p[h];
    for (int o2 = 32; o2; o2 >>= 1) v += __shfl_down(v, o2);
    if (lane == 0) outl[(long)node * 8 + h] = v;
  }
}

__global__ __launch_bounds__(256) void att_logits4(const float* __restrict__ X,
                                                   const float* __restrict__ v0, const float* __restrict__ v1,
                                                   const float* __restrict__ v2, const float* __restrict__ v3,
                                                   float* __restrict__ o0, float* __restrict__ o1,
                                                   float* __restrict__ o2, float* __restrict__ o3, int N) {
  const int lane = threadIdx.x & 63;
  const int node = blockIdx.x * 4 + (threadIdx.x >> 6);
  if (node >= N) return;
  const float* xr = X + (long)node * 640;
  float p[4][8];
#pragma unroll
  for (int s = 0; s < 4; ++s)
#pragma unroll
    for (int h = 0; h < 8; ++h) p[s][h] = 0.f;
  for (int k = lane; k < 640; k += 64) {
    const float xv = xr[k];
#pragma unroll
    for (int h = 0; h < 8; ++h) {
      p[0][h] += xv * v0[h * 640 + k];
      p[1][h] += xv * v1[h * 640 + k];
      p[2][h] += xv * v2[h * 640 + k];
      p[3][h] += xv * v3[h * 640 + k];
    }
  }
  float* outs[4] = {o0, o1, o2, o3};
#pragma unroll
  for (int s = 0; s < 4; ++s)
#pragma unroll
    for (int h = 0; h < 8; ++h) {
      float v = p[s][h];
      for (int o2v = 32; o2v; o2v >>= 1) v += __shfl_down(v, o2v);
      if (lane == 0) outs[s][(long)node * 8 + h] = v;
    }
}

// ---------------------------------------------------------------------------
// CSR build (3 edge lists per launch)
// ---------------------------------------------------------------------------
__global__ __launch_bounds__(256) void edge_count3(const int* __restrict__ d0, int E0, int* __restrict__ c0,
                                                   const int* __restrict__ d1, int E1, int* __restrict__ c1,
                                                   const int* __restrict__ d2, int E2, int* __restrict__ c2) {
  const int gid = blockIdx.x * blockDim.x + threadIdx.x;
  if (gid < E0) atomicAdd(&c0[d0[gid]], 1);
  else if (gid < E0 + E1) atomicAdd(&c1[d1[gid - E0]], 1);
  else if (gid < E0 + E1 + E2) atomicAdd(&c2[d2[gid - E0 - E1]], 1);
}

__global__ __launch_bounds__(1024) void scan_off3(const int* __restrict__ c0, int* __restrict__ o0,
                                                  const int* __restrict__ c1, int* __restrict__ o1,
                                                  const int* __restrict__ c2, int* __restrict__ o2) {
  const int* cnt = blockIdx.x == 0 ? c0 : (blockIdx.x == 1 ? c1 : c2);
  int* offo = blockIdx.x == 0 ? o0 : (blockIdx.x == 1 ? o1 : o2);
  __shared__ int part[1024];
  const int tid = threadIdx.x;
  const int base = tid * 8;
  int loc[8];
  int s = 0;
#pragma unroll
  for (int i = 0; i < 8; ++i) { loc[i] = s; s += cnt[base + i]; }
  part[tid] = s;
  __syncthreads();
  for (int d2 = 1; d2 < 1024; d2 <<= 1) {
    int v = (tid >= d2) ? part[tid - d2] : 0;
    __syncthreads();
    part[tid] += v;
    __syncthreads();
  }
  const int pre = (tid > 0) ? part[tid - 1] : 0;
#pragma unroll
  for (int i = 0; i < 8; ++i) offo[base + i] = pre + loc[i];
  if (tid == 1023) offo[8192] = part[1023];
}

__global__ __launch_bounds__(256) void edge_fill3(
    const int* __restrict__ s0, const int* __restrict__ d0, int E0, const int* __restrict__ of0, int* __restrict__ cu0, int* __restrict__ sr0,
    const int* __restrict__ s1, const int* __restrict__ d1, int E1, const int* __restrict__ of1, int* __restrict__ cu1, int* __restrict__ sr1,
    const int* __restrict__ s2, const int* __restrict__ d2, int E2, const int* __restrict__ of2, int* __restrict__ cu2, int* __restrict__ sr2) {
  const int gid = blockIdx.x * blockDim.x + threadIdx.x;
  if (gid < E0) {
    const int d = d0[gid];
    sr0[of0[d] + atomicAdd(&cu0[d], 1)] = s0[gid];
  } else if (gid < E0 + E1) {
    const int g = gid - E0, d = d1[g];
    sr1[of1[d] + atomicAdd(&cu1[d], 1)] = s1[g];
  } else if (gid < E0 + E1 + E2) {
    const int g = gid - E0 - E1, d = d2[g];
    sr2[of2[d] + atomicAdd(&cu2[d], 1)] = s2[g];
  }
}

// ---------------------------------------------------------------------------
// GAT aggregation, f32 X (float4) -- word layer (F=300)
// ---------------------------------------------------------------------------
template <int FPAD, int F, bool XPH, bool BIASELU>
__global__ __launch_bounds__(256) void gat_agg(const int* __restrict__ seg_off, const int* __restrict__ ssrc,
                                               const float* __restrict__ als, const float* __restrict__ ald,
                                               const float* __restrict__ X, int ldx,
                                               __bf16* __restrict__ outp, int ldo,
                                               const float* __restrict__ bias) {
  constexpr int C4 = F / 4;
  constexpr int ITEMS = 8 * C4;
  constexpr int L = (ITEMS + 255) / 256;
  const int d = blockIdx.x;
  const int tid = threadIdx.x;
  const int o0 = seg_off[d], o1 = seg_off[d + 1];
  const int deg = o1 - o0;
  __shared__ float exl[64][8];
  __shared__ int ssl[64];
  __shared__ float aldd[8];
  __shared__ float den_s[8];
  if (tid < 8) { aldd[tid] = ald[(long)d * 8 + tid]; den_s[tid] = 0.f; }
  f32x4 acc[L];
  int hh[L], xo[L], oo[L];
  bool vld[L];
#pragma unroll
  for (int l = 0; l < L; ++l) {
    const int idx = tid + l * 256;
    vld[l] = (idx < ITEMS);
    const int h = vld[l] ? (idx / C4) : 0;
    const int c = vld[l] ? (idx - h * C4) : 0;
    hh[l] = h;
    xo[l] = (XPH ? h * F : 0) + c * 4;
    oo[l] = h * FPAD + c * 4;
#pragma unroll
    for (int r = 0; r < 4; ++r) acc[l][r] = 0.f;
  }
  __syncthreads();
  for (int base = 0; base < deg; base += 64) {
    const int nc = min(64, deg - base);
    if (tid < nc) ssl[tid] = ssrc[o0 + base + tid];
    __syncthreads();
    for (int t = tid; t < nc * 8; t += 256) {
      const int e = t >> 3, h = t & 7;
      float v = als[(long)ssl[e] * 8 + h] + aldd[h];
      v = v > 0.f ? v : 0.2f * v;
      exl[e][h] = __expf(v);
    }
    __syncthreads();
    if (tid < 8) {
      float s = 0.f;
      for (int e = 0; e < nc; ++e) s += exl[e][tid];
      den_s[tid] += s;
    }
    for (int e = 0; e < nc; ++e) {
      const float* xr = X + (long)ssl[e] * ldx;
      const float* ex8 = exl[e];
#pragma unroll
      for (int l = 0; l < L; ++l)
        if (vld[l]) {
          const f32x4 v = *(const f32x4*)(xr + xo[l]);
          acc[l] += ex8[hh[l]] * v;
        }
    }
    __syncthreads();
  }
#pragma unroll
  for (int l = 0; l < L; ++l) {
    if (!vld[l]) continue;
    const float dinv = 1.f / (den_s[hh[l]] + 1e-16f);
#pragma unroll
    for (int j = 0; j < 4; ++j) {
      float r = acc[l][j] * dinv;
      if constexpr (BIASELU) { r += bias[oo[l] + j]; r = eluf(r); }
      outp[(long)d * ldo + oo[l] + j] = (__bf16)r;
    }
  }
}

// ---------------------------------------------------------------------------
// GAT aggregation, bf16 X (bf16x8) -- sentence & section layers
// ---------------------------------------------------------------------------
template <int FPAD, int F, bool XPH, bool BIASELU>
__global__ __launch_bounds__(256) void gat_agg_bf(const int* __restrict__ seg_off, const int* __restrict__ ssrc,
                                                  const float* __restrict__ als, const float* __restrict__ ald,
                                                  const __bf16* __restrict__ X, int ldx,
                                                  __bf16* __restrict__ outp, int ldo,
                                                  const float* __restrict__ bias) {
  constexpr int C8 = F / 8;
  constexpr int ITEMS = 8 * C8;
  constexpr int L = (ITEMS + 255) / 256;
  const int d = blockIdx.x;
  const int tid = threadIdx.x;
  const int o0 = seg_off[d], o1 = seg_off[d + 1];
  const int deg = o1 - o0;
  __shared__ float exl[64][8];
  __shared__ int ssl[64];
  __shared__ float aldd[8];
  __shared__ float den_s[8];
  if (tid < 8) { aldd[tid] = ald[(long)d * 8 + tid]; den_s[tid] = 0.f; }
  float acc[L][8];
  int hh[L], xo[L], oo[L];
  bool vld[L];
#pragma unroll
  for (int l = 0; l < L; ++l) {
    const int idx = tid + l * 256;
    vld[l] = (idx < ITEMS);
    const int h = vld[l] ? (idx / C8) : 0;
    const int c = vld[l] ? (idx - h * C8) : 0;
    hh[l] = h;
    xo[l] = (XPH ? h * F : 0) + c * 8;
    oo[l] = h * FPAD + c * 8;
#pragma unroll
    for (int r = 0; r < 8; ++r) acc[l][r] = 0.f;
  }
  __syncthreads();
  for (int base = 0; base < deg; base += 64) {
    const int nc = min(64, deg - base);
    if (tid < nc) ssl[tid] = ssrc[o0 + base + tid];
    __syncthreads();
    for (int t = tid; t < nc * 8; t += 256) {
      const int e = t >> 3, h = t & 7;
      float v = als[(long)ssl[e] * 8 + h] + aldd[h];
      v = v > 0.f ? v : 0.2f * v;
      exl[e][h] = __expf(v);
    }
    __syncthreads();
    if (tid < 8) {
      float s = 0.f;
      for (int e = 0; e < nc; ++e) s += exl[e][tid];
      den_s[tid] += s;
    }
    for (int e = 0; e < nc; ++e) {
      const __bf16* xr = X + (long)ssl[e] * ldx;
      const float* ex8 = exl[e];
#pragma unroll
      for (int l = 0; l < L; ++l)
        if (vld[l]) {
          const bf16x8 v = *(const bf16x8*)(xr + xo[l]);
          const float w = ex8[hh[l]];
#pragma unroll
          for (int r = 0; r < 8; ++r) acc[l][r] += w * (float)v[r];
        }
    }
    __syncthreads();
  }
#pragma unroll
  for (int l = 0; l < L; ++l) {
    if (!vld[l]) continue;
    const float dinv = 1.f / (den_s[hh[l]] + 1e-16f);
#pragma unroll
    for (int j = 0; j < 8; ++j) {
      float r = acc[l][j] * dinv;
      if constexpr (BIASELU) { r += bias[oo[l] + j]; r = eluf(r); }
      outp[(long)d * ldo + oo[l] + j] = (__bf16)r;
    }
  }
}

// ---------------------------------------------------------------------------
// 128x128-tile MFMA GEMM (m97-class, 2-barrier) -- small/batched GEMMs.
// EPI: 0 store f32 | 1 bias+ELU->bf16 | 2 sigmoid-gate mix->bf16
//      3 bias->bf16 | 4 bias+residual->f32 | 5 store bf16
// ---------------------------------------------------------------------------
template <int EPI>
__global__ __launch_bounds__(256) void gemm_bt(
    const __bf16* __restrict__ A, int lda, const __bf16* __restrict__ A2, int ksplit,
    const __bf16* __restrict__ Bt, int ldb, int K,
    void* __restrict__ Cout, int ldc,
    const float* __restrict__ bias,
    const __bf16* __restrict__ Xg, const __bf16* __restrict__ Yg, int ldxy,
    const float* __restrict__ Res, int ldres,
    long a_zs, long bt_zs, long c_zs, int b_zs) {
  __shared__ __bf16 sA[2][128 * 32];
  __shared__ __bf16 sB[2][128 * 32];
  const int tid = threadIdx.x;
  const int z = blockIdx.z;
  const int m0 = blockIdx.y * 128, n0 = blockIdx.x * 128;
  const __bf16* Ab = A + (long)z * a_zs;
  const __bf16* A2b = A2 ? A2 + (long)z * a_zs : nullptr;
  const __bf16* Btb = Bt + (long)z * bt_zs;
  const int lane = tid & 63;
  const int wv = tid >> 6, wr = wv >> 1, wc = wv & 1;
  const int fr = lane & 15, fq = lane >> 4;

  const int r0 = tid >> 2, r1 = r0 + 64;
  const int csw = (((tid & 3) ^ ((r0 >> 1) & 3)) * 8);
  const int ldst0 = tid * 8;
  const int ldst1 = 2048 + tid * 8;

  f32x4 acc[4][4];
#pragma unroll
  for (int i = 0; i < 4; ++i)
#pragma unroll
    for (int j = 0; j < 4; ++j)
#pragma unroll
      for (int r = 0; r < 4; ++r) acc[i][j][r] = 0.f;

  const int fsw = (fq ^ ((fr >> 1) & 3)) * 8;
  int aof[4], bof[4];
#pragma unroll
  for (int i = 0; i < 4; ++i) {
    aof[i] = (wr * 64 + i * 16 + fr) * 32 + fsw;
    bof[i] = (wc * 64 + i * 16 + fr) * 32 + fsw;
  }

  const int nkt = K >> 5;
  auto stage = [&](int buf, int kt) {
    const int k0 = kt * 32;
    const __bf16* As = Ab;
    int kr = k0;
    if (A2b && k0 >= ksplit) { As = A2b; kr = k0 - ksplit; }
    gload16(As + (long)(m0 + r0) * lda + kr + csw, &sA[buf][ldst0]);
    gload16(As + (long)(m0 + r1) * lda + kr + csw, &sA[buf][ldst1]);
    gload16(Btb + (long)(n0 + r0) * ldb + k0 + csw, &sB[buf][ldst0]);
    gload16(Btb + (long)(n0 + r1) * ldb + k0 + csw, &sB[buf][ldst1]);
  };

  stage(0, 0);
  for (int kt = 0; kt < nkt; ++kt) {
    const int cur = kt & 1;
    __syncthreads();
    if (kt + 1 < nkt) stage(cur ^ 1, kt + 1);
    bf16x8 af[4], bfv[4];
#pragma unroll
    for (int i = 0; i < 4; ++i) {
      af[i] = *(const bf16x8*)(&sA[cur][aof[i]]);
      bfv[i] = *(const bf16x8*)(&sB[cur][bof[i]]);
    }
#pragma unroll
    for (int i = 0; i < 4; ++i)
#pragma unroll
      for (int j = 0; j < 4; ++j)
        acc[i][j] = __builtin_amdgcn_mfma_f32_16x16x32_bf16(af[i], bfv[j], acc[i][j], 0, 0, 0);
  }

  const float* biasb = bias ? bias + (long)z * b_zs : nullptr;
#pragma unroll
  for (int i = 0; i < 4; ++i) {
#pragma unroll
    for (int j = 0; j < 4; ++j) {
#pragma unroll
      for (int r = 0; r < 4; ++r) {
        const int mm = m0 + wr * 64 + i * 16 + fq * 4 + r;
        const int nn = n0 + wc * 64 + j * 16 + fr;
        const float v = acc[i][j][r];
        const long cidx = (long)mm * ldc + nn + (long)z * c_zs;
        if constexpr (EPI == 0) {
          ((float*)Cout)[cidx] = v;
        } else if constexpr (EPI == 1) {
          ((__bf16*)Cout)[cidx] = (__bf16)eluf(v + biasb[nn]);
        } else if constexpr (EPI == 2) {
          const float zt = sigmf(v + biasb[nn]);
          const float x = (float)Xg[(long)mm * ldxy + nn];
          const float y = (float)Yg[(long)mm * ldxy + nn];
          ((__bf16*)Cout)[cidx] = (__bf16)(zt * x + (1.f - zt) * y);
        } else if constexpr (EPI == 3) {
          ((__bf16*)Cout)[cidx] = (__bf16)(v + biasb[nn]);
        } else if constexpr (EPI == 4) {
          ((float*)Cout)[cidx] = v + biasb[nn] + Res[(long)mm * ldres + nn];
        } else {
          ((__bf16*)Cout)[cidx] = (__bf16)v;
        }
      }
    }
  }
}

// ---------------------------------------------------------------------------
// 256x256-tile 8-wave MFMA GEMM, hoisted-reads pipeline (R7/R10 structure,
// FROZEN -- proven ~945us / MfmaUtil 44% / 0 bank conflicts).
// ---------------------------------------------------------------------------
template <int EPI>
__global__ __launch_bounds__(512, 2) void gemm256(
    const __bf16* __restrict__ A, int lda, const __bf16* __restrict__ A2, int ksplit,
    const __bf16* __restrict__ Bt, int ldb, int K,
    void* __restrict__ Cout, int ldc,
    const float* __restrict__ bias,
    const __bf16* __restrict__ Xg, const __bf16* __restrict__ Yg, int ldxy,
    int nn_tiles) {
  __shared__ __bf16 sA[2][2][256 * 32];
  __shared__ __bf16 sB[2][2][256 * 32];
  const int tid = threadIdx.x;

  const int nwg = gridDim.x;
  const int lin = blockIdx.x;
  const int qq = nwg >> 3, rr = nwg & 7;
  const int xcd = lin & 7, pos = lin >> 3;
  const int swz = (xcd < rr ? xcd * (qq + 1) : rr * (qq + 1) + (xcd - rr) * qq) + pos;
  const int m0 = (swz / nn_tiles) * 256;
  const int n0 = (swz % nn_tiles) * 256;

  const int lane = tid & 63;
  const int wv = tid >> 6, wm = wv >> 2, wn = wv & 3;
  const int fr = lane & 15, fq = lane >> 4;

  const int srow = tid >> 2;
  const int pslot = tid & 3;

  auto stageA = [&](int bp, int tt, int kk) {
    const int kcol0 = tt * 64 + kk * 32;
    const __bf16* src = A;
    int kc = kcol0;
    if (A2 && kcol0 >= ksplit) { src = A2; kc = kcol0 - ksplit; }
    __bf16* dst = &sA[bp][kk][0];
#pragma unroll
    for (int i = 0; i < 2; ++i) {
      const int r = i * 128 + srow;
      const int l = pslot ^ ((r >> 1) & 3);
      gload16(src + (long)(m0 + r) * lda + kc + l * 8, dst + (i * 512 + tid) * 8);
    }
  };
  auto stageB = [&](int bp, int tt, int kk) {
    const int kcol0 = tt * 64 + kk * 32;
    __bf16* dst = &sB[bp][kk][0];
#pragma unroll
    for (int i = 0; i < 2; ++i) {
      const int r = i * 128 + srow;
      const int l = pslot ^ ((r >> 1) & 3);
      gload16(Bt + (long)(n0 + r) * ldb + kcol0 + l * 8, dst + (i * 512 + tid) * 8);
    }
  };

  int aoff[8], boff[4];
#pragma unroll
  for (int mf = 0; mf < 8; ++mf) {
    const int ra = wm * 128 + mf * 16 + fr;
    aoff[mf] = ra * 32 + ((fq ^ ((ra >> 1) & 3)) * 8);
  }
#pragma unroll
  for (int nf = 0; nf < 4; ++nf) {
    const int rb = wn * 64 + nf * 16 + fr;
    boff[nf] = rb * 32 + ((fq ^ ((rb >> 1) & 3)) * 8);
  }

  f32x4 acc[8][4];
#pragma unroll
  for (int i = 0; i < 8; ++i)
#pragma unroll
    for (int j = 0; j < 4; ++j)
#pragma unroll
      for (int r = 0; r < 4; ++r) acc[i][j][r] = 0.f;

  const int nkt = K >> 6;

  bf16x8 aA[4], aB[4], bA[4], bB[4];

  stageA(0, 0, 0); stageB(0, 0, 0); stageA(0, 0, 1); stageB(0, 0, 1);
  asm volatile("s_waitcnt vmcnt(4)" ::: "memory");
  __builtin_amdgcn_s_barrier();
#pragma unroll
  for (int mf = 0; mf < 4; ++mf) aA[mf] = *(const bf16x8*)(&sA[0][0][aoff[mf]]);
#pragma unroll
  for (int nf = 0; nf < 4; ++nf) bA[nf] = *(const bf16x8*)(&sB[0][0][boff[nf]]);

  for (int t = 0; t < nkt; ++t) {
    const int cb = t & 1, nb = cb ^ 1;
    const bool pf = (t + 1 < nkt);

    // q1 reads (cb k0, A 4-7) -- hoisted above q0 MFMA
#pragma unroll
    for (int mf = 0; mf < 4; ++mf) aB[mf] = *(const bf16x8*)(&sA[cb][0][aoff[4 + mf]]);
    if (pf) stageA(nb, t + 1, 0);
    asm volatile("s_waitcnt lgkmcnt(4)" ::: "memory");
    __builtin_amdgcn_sched_barrier(0);
    __builtin_amdgcn_s_setprio(1);
#pragma unroll
    for (int mf = 0; mf < 4; ++mf)
#pragma unroll
      for (int nf = 0; nf < 4; ++nf)
        acc[mf][nf] = __builtin_amdgcn_mfma_f32_16x16x32_bf16(aA[mf], bA[nf], acc[mf][nf], 0, 0, 0);
    __builtin_amdgcn_s_setprio(0);
    __builtin_amdgcn_sched_barrier(0);

    if (pf) stageB(nb, t + 1, 0);
    if (pf) asm volatile("s_waitcnt vmcnt(4)" ::: "memory");
    else    asm volatile("s_waitcnt vmcnt(0)" ::: "memory");
    __builtin_amdgcn_s_barrier();  // B1: cb k1 valid

    // q2 reads (cb k1, A 0-3 + B 0-3) -- hoisted above q1 MFMA
#pragma unroll
    for (int mf = 0; mf < 4; ++mf) aA[mf] = *(const bf16x8*)(&sA[cb][1][aoff[mf]]);
#pragma unroll
    for (int nf = 0; nf < 4; ++nf) bB[nf] = *(const bf16x8*)(&sB[cb][1][boff[nf]]);
    asm volatile("s_waitcnt lgkmcnt(8)" ::: "memory");
    __builtin_amdgcn_sched_barrier(0);
    __builtin_amdgcn_s_setprio(1);
#pragma unroll
    for (int mf = 0; mf < 4; ++mf)
#pragma unroll
      for (int nf = 0; nf < 4; ++nf)
        acc[4 + mf][nf] = __builtin_amdgcn_mfma_f32_16x16x32_bf16(aB[mf], bA[nf], acc[4 + mf][nf], 0, 0, 0);
    __builtin_amdgcn_s_setprio(0);
    __builtin_amdgcn_sched_barrier(0);

    // q3 reads (cb k1, A 4-7) -- hoisted above q2 MFMA
#pragma unroll
    for (int mf = 0; mf < 4; ++mf) aB[mf] = *(const bf16x8*)(&sA[cb][1][aoff[4 + mf]]);
    if (pf) stageA(nb, t + 1, 1);
    asm volatile("s_waitcnt lgkmcnt(4)" ::: "memory");
    __builtin_amdgcn_sched_barrier(0);
    __builtin_amdgcn_s_setprio(1);
#pragma unroll
    for (int mf = 0; mf < 4; ++mf)
#pragma unroll
      for (int nf = 0; nf < 4; ++nf)
        acc[mf][nf] = __builtin_amdgcn_mfma_f32_16x16x32_bf16(aA[mf], bB[nf], acc[mf][nf], 0, 0, 0);
    __builtin_amdgcn_s_setprio(0);
    __builtin_amdgcn_sched_barrier(0);

    if (pf) {
      stageB(nb, t + 1, 1);
      asm volatile("s_waitcnt vmcnt(4)" ::: "memory");
    }
    __builtin_amdgcn_s_barrier();  // B3: nb k0 valid

    // next-tile q0 reads (nb k0) -- hoisted above q3 MFMA
    if (pf) {
#pragma unroll
      for (int mf = 0; mf < 4; ++mf) aA[mf] = *(const bf16x8*)(&sA[nb][0][aoff[mf]]);
#pragma unroll
      for (int nf = 0; nf < 4; ++nf) bA[nf] = *(const bf16x8*)(&sB[nb][0][boff[nf]]);
      asm volatile("s_waitcnt lgkmcnt(8)" ::: "memory");
    } else {
      asm volatile("s_waitcnt lgkmcnt(0)" ::: "memory");
    }
    __builtin_amdgcn_sched_barrier(0);
    __builtin_amdgcn_s_setprio(1);
#pragma unroll
    for (int mf = 0; mf < 4; ++mf)
#pragma unroll
      for (int nf = 0; nf < 4; ++nf)
        acc[4 + mf][nf] = __builtin_amdgcn_mfma_f32_16x16x32_bf16(aB[mf], bB[nf], acc[4 + mf][nf], 0, 0, 0);
    __builtin_amdgcn_s_setprio(0);
    __builtin_amdgcn_sched_barrier(0);
  }

  // epilogue
#pragma unroll
  for (int mf = 0; mf < 8; ++mf) {
#pragma unroll
    for (int nf = 0; nf < 4; ++nf) {
#pragma unroll
      for (int r = 0; r < 4; ++r) {
        const int mm = m0 + wm * 128 + mf * 16 + fq * 4 + r;
        const int nn = n0 + wn * 64 + nf * 16 + fr;
        const float v = acc[mf][nf][r];
        const long cidx = (long)mm * ldc + nn;
        if constexpr (EPI == 2) {
          const float zt = sigmf(v + bias[nn]);
          const float x = (float)Xg[(long)mm * ldxy + nn];
          const float y = (float)Yg[(long)mm * ldxy + nn];
          ((__bf16*)Cout)[cidx] = (__bf16)(zt * x + (1.f - zt) * y);
        } else {
          ((__bf16*)Cout)[cidx] = (__bf16)(v + bias[nn]);
        }
      }
    }
  }
}

// ---------------------------------------------------------------------------
extern "C" void kernel_launch(void* const* d_in, const int* in_sizes, int n_in,
                              void* d_out, int out_size, void* d_ws, size_t ws_size,
                              hipStream_t stream) {
  (void)in_sizes; (void)n_in; (void)out_size;
  const float* Hs    = (const float*)d_in[0];
  const float* Hw    = (const float*)d_in[1];
  const float* HSec  = (const float*)d_in[2];
  const int* w2s     = (const int*)d_in[3];
  const int* s2s     = (const int*)d_in[4];
  const int* S2s     = (const int*)d_in[5];
  const float* Ww_src = (const float*)d_in[6];
  const float* Ww_dst = (const float*)d_in[7];
  const float* aw_src = (const float*)d_in[8];
  const float* aw_dst = (const float*)d_in[9];
  const float* bw     = (const float*)d_in[10];
  const float* Wss    = (const float*)d_in[11];
  const float* as_src = (const float*)d_in[12];
  const float* as_dst = (const float*)d_in[13];
  const float* bs     = (const float*)d_in[14];
  const float* WS_src = (const float*)d_in[15];
  const float* WS_dst = (const float*)d_in[16];
  const float* aS_src = (const float*)d_in[17];
  const float* aS_dst = (const float*)d_in[18];
  const float* bS     = (const float*)d_in[19];
  const float* F1_w   = (const float*)d_in[20];
  const float* F1_b   = (const float*)d_in[21];
  const float* F2_w   = (const float*)d_in[22];
  const float* F2_b   = (const float*)d_in[23];
  const float* l1_w   = (const float*)d_in[24];
  const float* l1_b   = (const float*)d_in[25];
  const float* l2_w   = (const float*)d_in[26];
  const float* l2_b   = (const float*)d_in[27];
  float* outp = (float*)d_out;

  char* ws = (char*)d_ws;
  size_t cur_off = 0;
  auto alloc = [&](size_t bytes) -> char* {
    char* p = ws + cur_off;
    cur_off = (cur_off + bytes + 255) & ~(size_t)255;
    return p;
  };

  __bf16* Wt_w  = (__bf16*)alloc((size_t)5120 * 320 * 2);
  __bf16* Wt_s  = (__bf16*)alloc((size_t)5120 * 640 * 2);
  __bf16* Wt_S  = (__bf16*)alloc((size_t)5120 * 512 * 2);
  __bf16* WtF   = (__bf16*)alloc((size_t)5120 * 10240 * 2);  // F1 (and F2 in fallback)
  __bf16* Wt_l2 = (__bf16*)alloc((size_t)640 * 2048 * 2);
  __bf16* l1_bf = (__bf16*)alloc((size_t)5120 * 2048 * 2);
  __bf16* WcT   = (__bf16*)alloc((size_t)640 * 5120 * 2);
  float*  bc    = (float*)alloc(640 * 4);
  __bf16* HS_bf = (__bf16*)alloc((size_t)1024 * 512 * 2);
  __bf16* Hs_bf = (__bf16*)alloc((size_t)kNS * 640 * 2);
  float* v_w = (float*)alloc(8 * 320 * 4);
  float* u_w = (float*)alloc(8 * 640 * 4);
  float* v_s = (float*)alloc(8 * 640 * 4);
  float* u_s = (float*)alloc(8 * 640 * 4);
  float* v_S = (float*)alloc(8 * 512 * 4);
  float* u_S = (float*)alloc(8 * 640 * 4);
  float* alw_s = (float*)alloc((size_t)kNW * 8 * 4);
  float* alw_d = (float*)alloc((size_t)kNS * 8 * 4);
  float* als_s = (float*)alloc((size_t)kNS * 8 * 4);
  float* als_d = (float*)alloc((size_t)kNS * 8 * 4);
  float* alS_s = (float*)alloc((size_t)kNSEC * 8 * 4);
  float* alS_d = (float*)alloc((size_t)kNS * 8 * 4);
  int* csr_i  = (int*)alloc((size_t)6 * kNS * 4);
  int* cnt_w = csr_i, *cnt_s = csr_i + kNS, *cnt_S = csr_i + 2 * kNS;
  int* cur_w = csr_i + 3 * kNS, *cur_s = csr_i + 4 * kNS, *cur_S = csr_i + 5 * kNS;
  int* off_w = (int*)alloc((size_t)(kNS + 1) * 4);
  int* off_s = (int*)alloc((size_t)(kNS + 1) * 4);
  int* off_S = (int*)alloc((size_t)(kNS + 1) * 4);
  int* ssrc_w = (int*)alloc((size_t)kEW * 4);
  int* ssrc_s = (int*)alloc((size_t)kES * 4);
  int* ssrc_S = (int*)alloc((size_t)kESEC * 4);
  __bf16* hs_Sb = (__bf16*)alloc((size_t)1024 * 5120 * 2);
  char* aggreg = alloc((size_t)kNS * 2560 * 2 + (size_t)kNS * 5120 * 2);
  __bf16* agg_w = (__bf16*)aggreg;
  __bf16* agg_s = (__bf16*)(aggreg + (size_t)kNS * 2560 * 2);
  __bf16* U1 = (__bf16*)aggreg;  // alias (agg dead by fusion1)
  __bf16* Uw = (__bf16*)alloc((size_t)kNS * 5120 * 2);
  __bf16* Us = (__bf16*)alloc((size_t)kNS * 5120 * 2);
  __bf16* US = (__bf16*)alloc((size_t)kNS * 5120 * 2);
  __bf16* U2 = Uw;  // alias (Uw dead after fusion1)

  // optional second F buffer -> F2 transpose can run early (removes the
  // serial bubble between the two fusion GEMMs). R8 verified it fits.
  __bf16* WtF2 = nullptr;
  {
    const size_t f2b = (size_t)5120 * 10240 * 2;
    if (cur_off + f2b + 256 <= ws_size) WtF2 = (__bf16*)alloc(f2b);
  }

  const dim3 b256(256);

  // 1) weight conversions/transposes (F2 early if buffer available)
  conv_transpose<<<dim3(160, 5), b256, 0, stream>>>(Ww_src, 300, 5120, Wt_w, 320);
  conv_transpose<<<dim3(160, 10), b256, 0, stream>>>(Wss, 640, 5120, Wt_s, 640);
  conv_transpose<<<dim3(160, 8), b256, 0, stream>>>(WS_src, 512, 5120, Wt_S, 512);
  conv_transpose<<<dim3(160, 160), b256, 0, stream>>>(F1_w, 10240, 5120, WtF, 10240);
  if (WtF2) conv_transpose<<<dim3(160, 160), b256, 0, stream>>>(F2_w, 10240, 5120, WtF2, 10240);
  conv_transpose<<<dim3(20, 32), b256, 0, stream>>>(l2_w, 2048, 640, Wt_l2, 2048);
  conv_bf4<<<(1024 * 512 / 4 + 255) / 256, b256, 0, stream>>>(HSec, HS_bf, (long)1024 * 512 / 4);
  conv_bf4<<<((long)kNS * 640 / 4 + 255) / 256, b256, 0, stream>>>(Hs, Hs_bf, (long)kNS * 640 / 4);
  conv_bf4<<<((long)5120 * 2048 / 4 + 255) / 256, b256, 0, stream>>>(l1_w, l1_bf, (long)5120 * 2048 / 4);

  // 2) FFN collapse
  gemm_bt<5><<<dim3(40, 5, 1), b256, 0, stream>>>(
      Wt_l2, 2048, nullptr, 1 << 30, l1_bf, 2048, 2048,
      WcT, 5120, nullptr, nullptr, nullptr, 0, nullptr, 0, 0, 0, 0, 0);
  comb_bias<<<20, b256, 0, stream>>>(l1_b, l2_w, l2_b, bc);

  // 3) per-head attention vectors (6 jobs, one launch)
  {
    HVJobs jb;
    jb.j[0] = {Ww_src, aw_src, v_w, 300, 320};
    jb.j[1] = {Ww_dst, aw_dst, u_w, 640, 640};
    jb.j[2] = {Wss,    as_src, v_s, 640, 640};
    jb.j[3] = {Wss,    as_dst, u_s, 640, 640};
    jb.j[4] = {WS_src, aS_src, v_S, 512, 512};
    jb.j[5] = {WS_dst, aS_dst, u_S, 640, 640};
    head_vecs6<<<dim3(8, 160, 6), b256, 0, stream>>>(jb);
  }

  // 4) attention logits
  att_logits<<<(kNW + 3) / 4, b256, 0, stream>>>(Hw, 300, 300, v_w, 320, alw_s, kNW);
  att_logits<<<(kNSEC + 3) / 4, b256, 0, stream>>>(HSec, 512, 512, v_S, 512, alS_s, kNSEC);
  att_logits4<<<(kNS + 3) / 4, b256, 0, stream>>>(Hs, u_w, v_s, u_s, u_S,
                                                  alw_d, als_s, als_d, alS_d, kNS);

  // 5) CSR build (merged launches)
  hipMemsetAsync(csr_i, 0, (size_t)6 * kNS * 4, stream);
  edge_count3<<<(kEW + kES + kESEC + 255) / 256, b256, 0, stream>>>(
      w2s + kEW, kEW, cnt_w, s2s + kES, kES, cnt_s, S2s + kESEC, kESEC, cnt_S);
  scan_off3<<<3, 1024, 0, stream>>>(cnt_w, off_w, cnt_s, off_s, cnt_S, off_S);
  edge_fill3<<<(kEW + kES + kESEC + 255) / 256, b256, 0, stream>>>(
      w2s, w2s + kEW, kEW, off_w, cur_w, ssrc_w,
      s2s, s2s + kES, kES, off_s, cur_s, ssrc_s,
      S2s, S2s + kESEC, kESEC, off_S, cur_S, ssrc_S);

  // 6) section source transform: hs_Sb = HS @ WS_src  (bf16 out)
  gemm_bt<5><<<dim3(40, 8, 1), b256, 0, stream>>>(
      HS_bf, 512, nullptr, 1 << 30, Wt_S, 512, 512,
      hs_Sb, 5120, nullptr, nullptr, nullptr, 0, nullptr, 0, 0, 0, 0, 0);

  // 7) aggregations (w: f32/float4; s,S: bf16/bf16x8)
  gat_agg<320, 300, false, false><<<kNS, b256, 0, stream>>>(off_w, ssrc_w, alw_s, alw_d, Hw, 300, agg_w, 2560, nullptr);
  gat_agg_bf<640, 640, false, false><<<kNS, b256, 0, stream>>>(off_s, ssrc_s, als_s, als_d, Hs_bf, 640, agg_s, 5120, nullptr);
  gat_agg_bf<640, 640, true, true><<<kNS, b256, 0, stream>>>(off_S, ssrc_S, alS_s, alS_d, hs_Sb, 5120, US, 5120, bS);

  // 8) per-head GAT output GEMMs (+bias +ELU)
  gemm_bt<1><<<dim3(5, 64, 8), b256, 0, stream>>>(
      agg_w, 2560, nullptr, 1 << 30, Wt_w, 320, 320,
      Uw, 5120, bw, nullptr, nullptr, 0, nullptr, 0, 320, (long)640 * 320, 640, 640);
  gemm_bt<1><<<dim3(5, 64, 8), b256, 0, stream>>>(
      agg_s, 5120, nullptr, 1 << 30, Wt_s, 640, 640,
      Us, 5120, bs, nullptr, nullptr, 0, nullptr, 0, 640, (long)640 * 640, 640, 640);

  // 9) fusion 1: U1 = z*Uw + (1-z)*Us
  gemm256<2><<<dim3(640), dim3(512), 0, stream>>>(
      Uw, 5120, Us, 5120, WtF, 10240, 10240,
      U1, 5120, F1_b, Uw, Us, 5120, 20);

  // 10) fusion 2 -> U2 (F2 transpose already done early if WtF2; else here)
  if (!WtF2) conv_transpose<<<dim3(160, 160), b256, 0, stream>>>(F2_w, 10240, 5120, WtF, 10240);
  gemm256<2><<<dim3(640), dim3(512), 0, stream>>>(
      U1, 5120, US, 5120, WtF2 ? WtF2 : WtF, 10240, 10240,
      U2, 5120, F2_b, U1, US, 5120, 20);

  // 11) collapsed FFN: out = U2 @ Wc + bc + Hs
  gemm_bt<4><<<dim3(5, 64, 1), b256, 0, stream>>>(
      U2, 5120, nullptr, 1 << 30, WcT, 5120, 5120,
      outp, 640, bc, nullptr, nullptr, 0, Hs, 640, 0, 0, 0, 0);
}